// Round 2
// baseline (513.052 us; speedup 1.0000x reference)
//
#include <hip/hip_runtime.h>

typedef unsigned short u16;
typedef unsigned int u32;
typedef __bf16 bf16x8 __attribute__((ext_vector_type(8)));
typedef float f32x4 __attribute__((ext_vector_type(4)));

__device__ __forceinline__ u16 f2bf(float f) {
  u32 u = __builtin_bit_cast(u32, f);
  u = (u + 0x7fffu + ((u >> 16) & 1u)) >> 16;
  return (u16)u;
}
__device__ __forceinline__ float bf2f(u16 h) {
  return __builtin_bit_cast(float, ((u32)h) << 16);
}

// async global->LDS, 16B per lane; LDS dest = wave-uniform base + lane*16 [m97/m104]
__device__ __forceinline__ void gll16(const u16* g, u16* l) {
  __builtin_amdgcn_global_load_lds((const __attribute__((address_space(1))) void*)g,
                                   (__attribute__((address_space(3))) void*)l, 16, 0, 0);
}

// raw barrier: NO implicit vmcnt drain (the whole point of the counted pipeline)
__device__ __forceinline__ void barrier() {
  asm volatile("" ::: "memory");
  __builtin_amdgcn_s_barrier();
  asm volatile("" ::: "memory");
}
__device__ __forceinline__ void waitv8() { asm volatile("s_waitcnt vmcnt(8)" ::: "memory"); }
__device__ __forceinline__ void waitv0() { asm volatile("s_waitcnt vmcnt(0)" ::: "memory"); }

// ---------------- all fp32 -> bf16 conversions in one launch ----------------
__global__ __launch_bounds__(256) void cvt_all(const float* __restrict__ x,
                                               const float* __restrict__ WQ,
                                               const float* __restrict__ WK,
                                               const float* __restrict__ WV,
                                               const float* __restrict__ WO,
                                               const float* __restrict__ W1,
                                               const float* __restrict__ W2,
                                               u16* __restrict__ xb,
                                               u16* __restrict__ wqkvb,
                                               u16* __restrict__ wob,
                                               u16* __restrict__ w1b,
                                               u16* __restrict__ w2b) {
  const int S = 1 << 20;
  int i = (blockIdx.x * 256 + threadIdx.x) * 4;
  const float* src;
  u16* dst;
  if (i < 8 * S) { src = x + i; dst = xb + i; }
  else {
    int j = i - 8 * S;
    if (j < 3 * S)      { src = (j < S) ? WQ + j : (j < 2 * S) ? WK + (j - S) : WV + (j - 2 * S);
                          dst = wqkvb + j; }
    else if (j < 4 * S) { src = WO + (j - 3 * S); dst = wob + (j - 3 * S); }
    else if (j < 8 * S) { src = W1 + (j - 4 * S); dst = w1b + (j - 4 * S); }
    else                { src = W2 + (j - 8 * S); dst = w2b + (j - 8 * S); }
  }
  float4 v = *(const float4*)src;
  uint2 o;
  o.x = (u32)f2bf(v.x) | ((u32)f2bf(v.y) << 16);
  o.y = (u32)f2bf(v.z) | ((u32)f2bf(v.w) << 16);
  *(uint2*)dst = o;
}

// ---------------- 256x256 deep-pipelined bf16 MFMA GEMM: C = A @ W^T + bias ----------------
// 512 threads (8 waves, 2M x 4N), BK=32, ring-4 LDS slots (128 KiB total).
// Fragment-level software pipeline: each phase ISSUES the next phase's ds_reads
// BEFORE its MFMA cluster (sched_barrier(0) pins the order); the compiler's
// counted lgkmcnt before the MFMAs then waits only on reads issued a phase ago,
// so LDS drain overlaps MFMA [T3 interleave, m196]. Unroll-by-2 with named
// register sets X/Y keeps all fragment indexing static (rule #20).
// vmcnt(8) once per K-tile (stage B first, then wait) -> tile t+1 guaranteed
// staged when its reads are issued; never drains to 0 in the loop [T4].
// LDS chunk swizzle: phys chunk = logical ^ swizzle on BOTH sides (rule #21).
// QKV=1: N=3072 fused; seg0 = Q scaled 0.125*log2(e), seg1=K, seg2=V transposed.
// SPLIT=1: K halved, kz=0 -> C0 (+bias), kz=1 -> C1 (bf16 partials). N=1024 fixed.
template <int RELU, int QKV, int SPLIT>
__global__ __launch_bounds__(512, 2) void gemm256(const u16* __restrict__ A,
                                                  const u16* __restrict__ W,
                                                  const float* __restrict__ bias0,
                                                  void* __restrict__ C0,
                                                  int M, int N, int K,
                                                  const float* __restrict__ bias1,
                                                  void* __restrict__ C1,
                                                  const float* __restrict__ bias2,
                                                  void* __restrict__ C2,
                                                  int NBN) {
  __shared__ alignas(16) u16 lds[4 * 16384];  // 4 slots x (A 256x32 + B 256x32) u16 = 128 KiB
  const int tid = threadIdx.x;
  const int id = blockIdx.x;
  const int xcd = id & 7, r = id >> 3;
  int bm, bn, kz = 0, koff = 0, KL = K;
  if (SPLIT) {
    bn = (r & 3) << 8;            // N = 1024 fixed
    const int q = r >> 2;         // 0..7
    bm = ((q & 3) * 8 + xcd) << 8;
    kz = q >> 2;
    KL = K >> 1;
    koff = kz * KL;
  } else {
    bn = (r % NBN) << 8;
    bm = ((r / NBN) * 8 + xcd) << 8;
  }
  const int wave = tid >> 6, lane = tid & 63;
  const int lr = lane & 15, quad = lane >> 4;
  const int wm = (wave >> 2) << 7;  // 0 or 128
  const int wn = (wave & 3) << 6;   // 0,64,128,192

  // staging: each gll16 call-site = 8 waves x 1KB = one 128-row half of A or B.
  const int lrow = lane >> 2;
  const int lch = (lane & 3) ^ ((lane >> 3) & 3);  // logical chunk for linear phys dest
  const u16* Asrc = A + (size_t)(bm + wave * 16 + lrow) * K + koff + lch * 8;
  const u16* Wsrc = W + (size_t)(bn + wave * 16 + lrow) * K + koff + lch * 8;
  const size_t half = (size_t)128 * K;
  u16* dstbase = lds + wave * 512;  // u16 units; +4096 = second 128-row half

  const int NT = KL >> 5;
  const int fro = (quad ^ ((lr >> 1) & 3)) * 8;  // swizzled ds_read chunk offset (u16)
  f32x4 acc[8][4] = {};

#define STAGE_A(tt) { const int tp_ = ((tt) < NT) ? (tt) : NT - 1;               \
                      u16* d_ = dstbase + ((tt) & 3) * 16384;                    \
                      const size_t ko_ = (size_t)tp_ * 32;                       \
                      gll16(Asrc + ko_, d_); gll16(Asrc + ko_ + half, d_ + 4096); }
#define STAGE_B(tt) { const int tp_ = ((tt) < NT) ? (tt) : NT - 1;               \
                      u16* d_ = dstbase + ((tt) & 3) * 16384;                    \
                      const size_t ko_ = (size_t)tp_ * 32;                       \
                      gll16(Wsrc + ko_, d_ + 8192); gll16(Wsrc + ko_ + half, d_ + 12288); }
#define LDA(dst, slot, roff) { const u16* s_ = lds + (slot) * 16384;             \
    _Pragma("unroll") for (int mi_ = 0; mi_ < 4; mi_++)                          \
      dst[mi_] = *(const bf16x8*)(s_ + (wm + (roff) + mi_ * 16 + lr) * 32 + fro); }
#define LDB(dst, slot) { const u16* s_ = lds + (slot) * 16384 + 8192;            \
    _Pragma("unroll") for (int ni_ = 0; ni_ < 4; ni_++)                          \
      dst[ni_] = *(const bf16x8*)(s_ + (wn + ni_ * 16 + lr) * 32 + fro); }
#define MFMA16(AF, BF, O)                                                        \
    _Pragma("unroll") for (int mi_ = 0; mi_ < 4; mi_++)                          \
    _Pragma("unroll") for (int ni_ = 0; ni_ < 4; ni_++)                          \
      acc[(O) + mi_][ni_] = __builtin_amdgcn_mfma_f32_16x16x32_bf16(AF[mi_], BF[ni_], acc[(O) + mi_][ni_], 0, 0, 0);

  // prologue: stage tiles 0,1,2 (A then B per tile) = 12 loads/wave
  #pragma unroll
  for (int t = 0; t < 3; t++) {
    u16* d = dstbase + t * 16384;
    gll16(Asrc + (size_t)t * 32, d);
    gll16(Asrc + (size_t)t * 32 + half, d + 4096);
    gll16(Wsrc + (size_t)t * 32, d + 8192);
    gll16(Wsrc + (size_t)t * 32 + half, d + 12288);
  }
  waitv8();   // oldest 4 done = tile 0 fully staged; tiles 1,2 in flight
  barrier();

  bf16x8 aX[4], bX[4], aY[4], bY[4], a1f[4];
  LDA(aX, 0, 0);
  LDB(bX, 0);

  for (int t = 0; t < NT; t += 2) {
    // ---- tile t, phase 0: MFMA aX*bX; issue a1f (this tile's hi rows) ----
    STAGE_A(t + 3);
    barrier();
    LDA(a1f, t & 3, 64);
    __builtin_amdgcn_sched_barrier(0);
    __builtin_amdgcn_s_setprio(1);
    MFMA16(aX, bX, 0);
    __builtin_amdgcn_s_setprio(0);
    barrier();
    // ---- tile t, phase 1: MFMA a1f*bX; issue next tile's aY/bY ----
    STAGE_B(t + 3);
    waitv8();   // tiles <= t+1 fully staged ({A,B}(t+2),{A,B}(t+3) in flight)
    barrier();
    LDA(aY, (t + 1) & 3, 0);
    LDB(bY, (t + 1) & 3);
    __builtin_amdgcn_sched_barrier(0);
    __builtin_amdgcn_s_setprio(1);
    MFMA16(a1f, bX, 4);
    __builtin_amdgcn_s_setprio(0);
    barrier();
    // ---- tile t+1, phase 0: MFMA aY*bY; issue a1f ----
    STAGE_A(t + 4);
    barrier();
    LDA(a1f, (t + 1) & 3, 64);
    __builtin_amdgcn_sched_barrier(0);
    __builtin_amdgcn_s_setprio(1);
    MFMA16(aY, bY, 0);
    __builtin_amdgcn_s_setprio(0);
    barrier();
    // ---- tile t+1, phase 1: MFMA a1f*bY; issue tile t+2's aX/bX ----
    STAGE_B(t + 4);
    waitv8();
    barrier();
    LDA(aX, (t + 2) & 3, 0);
    LDB(bX, (t + 2) & 3);
    __builtin_amdgcn_sched_barrier(0);
    __builtin_amdgcn_s_setprio(1);
    MFMA16(a1f, bY, 4);
    __builtin_amdgcn_s_setprio(0);
    barrier();
  }
  waitv0();  // drain tail junk loads before LDS dealloc at endpgm

#undef STAGE_A
#undef STAGE_B
#undef LDA
#undef LDB
#undef MFMA16

  // epilogue: C/D layout col=lane&15, row=quad*4+reg [m89/m91]
  const float* bp = bias0;
  void* outp = C0;
  float scale = 1.0f;
  int cb = bn, Nout = N, seg = 0;
  if (QKV) {
    Nout = 1024;
    seg = bn >> 10;
    cb = bn & 1023;
    if (seg == 0) scale = 0.125f * 1.44269504089f;  // 1/sqrt(dk) * log2(e): attn uses exp2
    else if (seg == 1) { bp = bias1; outp = C1; }
    else { bp = bias2; outp = C2; }
  }
  if (SPLIT && kz) outp = C1;

  if (QKV && seg == 2) {
    // V: store transposed. 4 consecutive tokens per lane -> 8B packed stores.
    #pragma unroll
    for (int ni = 0; ni < 4; ni++) {
      const int col = cb + wn + ni * 16 + lr;
      const int hh = col >> 6, dl = col & 63;
      const float bv = bp[col];
      #pragma unroll
      for (int mi = 0; mi < 8; mi++) {
        const int row0 = bm + wm + mi * 16 + quad * 4;
        const int bb = row0 >> 11, tt = row0 & 2047;
        u16 pk[4];
        #pragma unroll
        for (int rg = 0; rg < 4; rg++) pk[rg] = f2bf(acc[mi][ni][rg] + bv);
        uint2 val;
        val.x = (u32)pk[0] | ((u32)pk[1] << 16);
        val.y = (u32)pk[2] | ((u32)pk[3] << 16);
        *(uint2*)(((u16*)outp) + ((size_t)((bb * 16 + hh) * 64 + dl)) * 2048 + tt) = val;
      }
    }
    return;
  }

  #pragma unroll
  for (int ni = 0; ni < 4; ni++) {
    const int col = cb + wn + ni * 16 + lr;
    const float bv = (SPLIT && kz) ? 0.0f : bp[col];
    #pragma unroll
    for (int mi = 0; mi < 8; mi++) {
      #pragma unroll
      for (int rg = 0; rg < 4; rg++) {
        int row = bm + wm + mi * 16 + quad * 4 + rg;
        float v = (acc[mi][ni][rg] + bv) * scale;
        if (RELU) v = fmaxf(v, 0.0f);
        ((u16*)outp)[(size_t)row * Nout + col] = f2bf(v);
      }
    }
  }
}

// ---------------- MFMA flash attention: shared k-sweep, S^T layout ----------------
// Block p handles q-tiles A=31-p and B=p with one k-sweep; K/V staged once.
// S^T = K Q^T via mfma(kf, qf): each lane then holds 16 P values for ITS query
// (query=lr, keys=nt*16+quad*4+rg) -> packed b64 P writes (v_perm pairs) and
// register row-sums for the denominator (no ones-MFMA, no shuffle per tile).
// Scores pre-scaled by log2(e)/8 -> P = exp2(s); no clamp needed (|s|<~5;
// mask -1e30 underflows exp2 to exactly 0). P truncated to bf16 (hi16).
constexpr int ALD = 72;  // sP row stride (u16)

__global__ __launch_bounds__(256) void attn_mfma(const u16* __restrict__ qb,
                                                 const u16* __restrict__ kb,
                                                 const u16* __restrict__ vt,
                                                 u16* __restrict__ ctxb, int T) {
  __shared__ alignas(16) u16 sK[64 * 64];
  __shared__ alignas(16) u16 sVt[64 * 64];
  __shared__ alignas(16) u16 sP[4 * 2 * 16 * ALD];
  const int tid = threadIdx.x;
  const int i = blockIdx.x;
  const int g = (i & 7) | (((i >> 7) & 7) << 3);  // all 16 p-blocks of g share i&7 (XCD)
  const int p = (i >> 3) & 15;
  const int h = g >> 2, b = g & 3;
  const size_t base = ((size_t)(b * T)) * 1024 + h * 64;
  const size_t vbase = ((size_t)((b * 16 + h) * 64)) * T;
  const int lane = tid & 63, wave = tid >> 6;
  const int lr = lane & 15, quad = lane >> 4;
  u16* sPA = sP + (wave * 2) * 16 * ALD;
  u16* sPB = sPA + 16 * ALD;

  const int srow = lane >> 3;
  const int sch = ((lane & 7) ^ srow) * 8;
  const int fsw = lr & 7;

  const int qtA = 31 - p, qtB = p;
  const int q0A = qtA * 64 + wave * 16, q0B = qtB * 64 + wave * 16;
  bf16x8 qfA[2], qfB[2];
  #pragma unroll
  for (int sl = 0; sl < 2; sl++) {
    uint4 uA = *(const uint4*)(qb + base + (size_t)(q0A + lr) * 1024 + sl * 32 + quad * 8);
    qfA[sl] = __builtin_bit_cast(bf16x8, uA);
    uint4 uB = *(const uint4*)(qb + base + (size_t)(q0B + lr) * 1024 + sl * 32 + quad * 8);
    qfB[sl] = __builtin_bit_cast(bf16x8, uB);
  }
  f32x4 oA[4] = {}, oB[4] = {};
  float smA[4] = {0, 0, 0, 0}, smB[4] = {0, 0, 0, 0};

  for (int kt = 0; kt <= qtA; kt++) {
    const bool doB = (kt <= qtB);
    __syncthreads();
    #pragma unroll
    for (int j = 0; j < 2; j++) {
      const int rowbase = (wave * 2 + j) * 8;
      const int r = rowbase + srow;
      gll16(kb + base + (size_t)(kt * 64 + r) * 1024 + sch, sK + rowbase * 64);
      gll16(vt + vbase + (size_t)r * T + (size_t)(kt * 64) + sch, sVt + rowbase * 64);
    }
    __syncthreads();

    // S^T = K Q^T (kf as A operand, shared between q-tiles); log2 units.
    // D: col=lane&15 -> query=lr, row=quad*4+rg -> key nt*16+quad*4+rg.
    f32x4 sa[4] = {}, sb[4] = {};
    #pragma unroll
    for (int sl = 0; sl < 2; sl++) {
      bf16x8 kf[4];
      #pragma unroll
      for (int nt = 0; nt < 4; nt++)
        kf[nt] = *(const bf16x8*)(sK + (nt * 16 + lr) * 64 + ((((sl << 2) | quad) ^ fsw) * 8));
      #pragma unroll
      for (int nt = 0; nt < 4; nt++)
        sa[nt] = __builtin_amdgcn_mfma_f32_16x16x32_bf16(kf[nt], qfA[sl], sa[nt], 0, 0, 0);
      if (doB) {
        #pragma unroll
        for (int nt = 0; nt < 4; nt++)
          sb[nt] = __builtin_amdgcn_mfma_f32_16x16x32_bf16(kf[nt], qfB[sl], sb[nt], 0, 0, 0);
      }
    }

    // causal masks on diagonal tiles: key (nt*16+quad*4+rg) > query (wave*16+lr)
    const int qloc = wave * 16 + lr;
    if (kt == qtA) {
      #pragma unroll
      for (int nt = 0; nt < 4; nt++)
        #pragma unroll
        for (int rg = 0; rg < 4; rg++)
          if (nt * 16 + quad * 4 + rg > qloc) sa[nt][rg] = -1e30f;
    }
    if (doB && kt == qtB) {
      #pragma unroll
      for (int nt = 0; nt < 4; nt++)
        #pragma unroll
        for (int rg = 0; rg < 4; rg++)
          if (nt * 16 + quad * 4 + rg > qloc) sb[nt][rg] = -1e30f;
    }

    // P = exp2(S), v_perm-packed truncated bf16, one b64 write per nt;
    // row-sum accumulated in registers (lane's own query).
    #pragma unroll
    for (int nt = 0; nt < 4; nt++) {
      float e0 = __builtin_amdgcn_exp2f(sa[nt][0]);
      float e1 = __builtin_amdgcn_exp2f(sa[nt][1]);
      float e2 = __builtin_amdgcn_exp2f(sa[nt][2]);
      float e3 = __builtin_amdgcn_exp2f(sa[nt][3]);
      smA[nt] += (e0 + e1) + (e2 + e3);
      uint2 pk;
      pk.x = __builtin_amdgcn_perm(__builtin_bit_cast(u32, e1), __builtin_bit_cast(u32, e0), 0x07060302u);
      pk.y = __builtin_amdgcn_perm(__builtin_bit_cast(u32, e3), __builtin_bit_cast(u32, e2), 0x07060302u);
      *(uint2*)(sPA + lr * ALD + nt * 16 + quad * 4) = pk;
    }
    if (doB) {
      #pragma unroll
      for (int nt = 0; nt < 4; nt++) {
        float e0 = __builtin_amdgcn_exp2f(sb[nt][0]);
        float e1 = __builtin_amdgcn_exp2f(sb[nt][1]);
        float e2 = __builtin_amdgcn_exp2f(sb[nt][2]);
        float e3 = __builtin_amdgcn_exp2f(sb[nt][3]);
        smB[nt] += (e0 + e1) + (e2 + e3);
        uint2 pk;
        pk.x = __builtin_amdgcn_perm(__builtin_bit_cast(u32, e1), __builtin_bit_cast(u32, e0), 0x07060302u);
        pk.y = __builtin_amdgcn_perm(__builtin_bit_cast(u32, e3), __builtin_bit_cast(u32, e2), 0x07060302u);
        *(uint2*)(sPB + lr * ALD + nt * 16 + quad * 4) = pk;
      }
    }
    asm volatile("" ::: "memory");  // wave-private: per-wave DS ordering suffices

    // O += P V  (vf shared between q-tiles)
    #pragma unroll
    for (int sl = 0; sl < 2; sl++) {
      bf16x8 vf[4];
      #pragma unroll
      for (int nt = 0; nt < 4; nt++)
        vf[nt] = *(const bf16x8*)(sVt + (nt * 16 + lr) * 64 + ((((sl << 2) | quad) ^ fsw) * 8));
      bf16x8 pfA = *(const bf16x8*)(sPA + lr * ALD + sl * 32 + quad * 8);
      #pragma unroll
      for (int nt = 0; nt < 4; nt++)
        oA[nt] = __builtin_amdgcn_mfma_f32_16x16x32_bf16(pfA, vf[nt], oA[nt], 0, 0, 0);
      if (doB) {
        bf16x8 pfB = *(const bf16x8*)(sPB + lr * ALD + sl * 32 + quad * 8);
        #pragma unroll
        for (int nt = 0; nt < 4; nt++)
          oB[nt] = __builtin_amdgcn_mfma_f32_16x16x32_bf16(pfB, vf[nt], oB[nt], 0, 0, 0);
      }
    }
  }

  // denominators: lane holds l for query=lr (4 partials); reduce across quads,
  // then shfl to the (quad*4+rg) distribution the C-layout epilogue needs.
  float sumA = (smA[0] + smA[1]) + (smA[2] + smA[3]);
  sumA += __shfl_xor(sumA, 16);
  sumA += __shfl_xor(sumA, 32);
  float sumB = (smB[0] + smB[1]) + (smB[2] + smB[3]);
  sumB += __shfl_xor(sumB, 16);
  sumB += __shfl_xor(sumB, 32);
  float invA[4], invB[4];
  #pragma unroll
  for (int rg = 0; rg < 4; rg++) {
    invA[rg] = 1.0f / __shfl(sumA, quad * 4 + rg);
    invB[rg] = 1.0f / __shfl(sumB, quad * 4 + rg);
  }
  #pragma unroll
  for (int nt = 0; nt < 4; nt++)
    #pragma unroll
    for (int rg = 0; rg < 4; rg++) {
      int qrow = q0A + quad * 4 + rg;
      ctxb[base + (size_t)qrow * 1024 + nt * 16 + lr] = f2bf(oA[nt][rg] * invA[rg]);
    }
  #pragma unroll
  for (int nt = 0; nt < 4; nt++)
    #pragma unroll
    for (int rg = 0; rg < 4; rg++) {
      int qrow = q0B + quad * 4 + rg;
      ctxb[base + (size_t)qrow * 1024 + nt * 16 + lr] = f2bf(oB[nt][rg] * invB[rg]);
    }
}

// ---------------- fused residual + split-K reduce (bf16 partials) + LayerNorm ----------------
// out = LN(a + b + c) * g + be ;  a is fp32 (ABF=0) or bf16 (ABF=1); b,c bf16 partials
template <int ABF>
__global__ __launch_bounds__(256) void ln_kernel(const void* __restrict__ a,
                                                 const u16* __restrict__ b,
                                                 const u16* __restrict__ c,
                                                 const float* __restrict__ g,
                                                 const float* __restrict__ be,
                                                 float* __restrict__ of32,
                                                 u16* __restrict__ obf) {
  const int row = blockIdx.x;
  const int tid = threadIdx.x;
  const size_t base = (size_t)row * 1024;
  const int cc = tid * 4;
  float a0, a1, a2, a3;
  if (ABF) {
    uint2 ua = *(const uint2*)((const u16*)a + base + cc);
    a0 = bf2f(ua.x & 0xffff); a1 = bf2f(ua.x >> 16);
    a2 = bf2f(ua.y & 0xffff); a3 = bf2f(ua.y >> 16);
  } else {
    float4 xa = *(const float4*)((const float*)a + base + cc);
    a0 = xa.x; a1 = xa.y; a2 = xa.z; a3 = xa.w;
  }
  uint2 ub = *(const uint2*)(b + base + cc);
  uint2 uc = *(const uint2*)(c + base + cc);
  float v0 = a0 + bf2f(ub.x & 0xffff) + bf2f(uc.x & 0xffff);
  float v1 = a1 + bf2f(ub.x >> 16)    + bf2f(uc.x >> 16);
  float v2 = a2 + bf2f(ub.y & 0xffff) + bf2f(uc.y & 0xffff);
  float v3 = a3 + bf2f(ub.y >> 16)    + bf2f(uc.y >> 16);
  float s1 = v0 + v1 + v2 + v3;
  float s2 = v0 * v0 + v1 * v1 + v2 * v2 + v3 * v3;
  for (int off = 1; off < 64; off <<= 1) {
    s1 += __shfl_xor(s1, off);
    s2 += __shfl_xor(s2, off);
  }
  __shared__ float red[8];
  int wv = tid >> 6;
  if ((tid & 63) == 0) { red[wv] = s1; red[4 + wv] = s2; }
  __syncthreads();
  s1 = red[0] + red[1] + red[2] + red[3];
  s2 = red[4] + red[5] + red[6] + red[7];
  float mu = s1 * (1.0f / 1024.0f);
  float var = s2 * (1.0f / 1024.0f) - mu * mu;
  float rs = rsqrtf(var + 1e-5f);
  float4 gv = *(const float4*)(g + cc);
  float4 bev = *(const float4*)(be + cc);
  float y0 = (v0 - mu) * rs * gv.x + bev.x;
  float y1 = (v1 - mu) * rs * gv.y + bev.y;
  float y2 = (v2 - mu) * rs * gv.z + bev.z;
  float y3 = (v3 - mu) * rs * gv.w + bev.w;
  if (of32) {
    float4 o = make_float4(y0, y1, y2, y3);
    *(float4*)(of32 + base + cc) = o;
  }
  if (obf) {
    uint2 o;
    o.x = (u32)f2bf(y0) | ((u32)f2bf(y1) << 16);
    o.y = (u32)f2bf(y2) | ((u32)f2bf(y3) << 16);
    *(uint2*)(obf + base + cc) = o;
  }
}

// ---------------- launch ----------------
extern "C" void kernel_launch(void* const* d_in, const int* in_sizes, int n_in,
                              void* d_out, int out_size, void* d_ws, size_t ws_size,
                              hipStream_t stream) {
  const int Mtok = 8192, D = 1024, F = 4096, T = 2048;
  const float* x   = (const float*)d_in[0];
  const float* WQ  = (const float*)d_in[1];
  const float* bQ  = (const float*)d_in[2];
  const float* WK  = (const float*)d_in[3];
  const float* bK  = (const float*)d_in[4];
  const float* WV  = (const float*)d_in[5];
  const float* bV  = (const float*)d_in[6];
  const float* WO  = (const float*)d_in[7];
  const float* bO  = (const float*)d_in[8];
  const float* W1  = (const float*)d_in[9];
  const float* b1  = (const float*)d_in[10];
  const float* W2  = (const float*)d_in[11];
  const float* b2  = (const float*)d_in[12];
  const float* g1  = (const float*)d_in[13];
  const float* be1 = (const float*)d_in[14];
  const float* g2  = (const float*)d_in[15];
  const float* be2 = (const float*)d_in[16];

  char* ws = (char*)d_ws;
  const size_t MB = 1024 * 1024;
  u16*  xb     = (u16*)(ws + 0);          // 16 MB (dead after QKV)
  u16*  wqkvb  = (u16*)(ws + 16 * MB);    // 6 MB  (dead after QKV)
  u16*  wob    = (u16*)(ws + 22 * MB);    // 2 MB  (dead after WO)
  u16*  w1b    = (u16*)(ws + 24 * MB);    // 8 MB  (dead after FF1)
  u16*  w2b    = (u16*)(ws + 32 * MB);    // 8 MB  (dead after FF2)
  u16*  qb     = (u16*)(ws + 40 * MB);    // 16 MB (dead after attn)
  u16*  kb     = (u16*)(ws + 56 * MB);    // 16 MB (dead after attn)
  u16*  vtb    = (u16*)(ws + 72 * MB);    // 16 MB, written transposed by QKV (dead after attn)
  u16*  ctxb   = (u16*)(ws + 88 * MB);    // 16 MB (dead after WO)
  u16*  wp0    = (u16*)(ws + 104 * MB);   // 16 MB bf16 partial (dead after ln1)
  u16*  wp1    = (u16*)(ws + 120 * MB);   // 16 MB bf16 partial (dead after ln1)
  u16*  h1b    = (u16*)(ws + 136 * MB);   // 16 MB bf16 LN1 output (live until ln2)
  u16*  ff1b   = (u16*)(ws + 40 * MB);    // 64 MB over qb..ctxb (dead after FF2)
  u16*  fp0    = (u16*)(ws + 0);          // 16 MB bf16 partial over xb
  u16*  fp1    = (u16*)(ws + 16 * MB);    // 16 MB bf16 partial over wqkvb/wob
  float* out   = (float*)d_out;

  dim3 blk(256);
  dim3 blk512(512);
  cvt_all<<<(20 << 20) / 1024, blk, 0, stream>>>(x, WQ, WK, WV, WO, W1, W2,
                                                 xb, wqkvb, wob, w1b, w2b);

  // fused QKV (N=3072): seg0=Q scaled log2(e)/8, seg1=K, seg2=V stored transposed
  gemm256<0, 1, 0><<<dim3(384), blk512, 0, stream>>>(xb, wqkvb, bQ, qb, Mtok, 3072, D,
                                                     bK, kb, bV, vtb, 12);
  attn_mfma<<<dim3(1024), blk, 0, stream>>>(qb, kb, vtb, ctxb, T);

  // WO projection, split-K=2 -> bf16 partials wp0/wp1; ln1 reduces
  gemm256<0, 0, 1><<<dim3(256), blk512, 0, stream>>>(ctxb, wob, bO, wp0, Mtok, D, D,
                                                     nullptr, wp1, nullptr, nullptr, 4);
  ln_kernel<0><<<Mtok, blk, 0, stream>>>(x, wp0, wp1, g1, be1, nullptr, h1b);

  gemm256<1, 0, 0><<<dim3(512), blk512, 0, stream>>>(h1b, w1b, b1, ff1b, Mtok, F, D,
                                                     nullptr, nullptr, nullptr, nullptr, 16);
  // FF2, split-K=2 -> bf16 partials fp0/fp1; ln2 reduces (bf16 residual h1b)
  gemm256<0, 0, 1><<<dim3(256), blk512, 0, stream>>>(ff1b, w2b, b2, fp0, Mtok, D, F,
                                                     nullptr, fp1, nullptr, nullptr, 4);
  ln_kernel<1><<<Mtok, blk, 0, stream>>>(h1b, fp0, fp1, g2, be2, out, (u16*)nullptr);
}

// Round 3
// 504.714 us; speedup vs baseline: 1.0165x; 1.0165x over previous
//
#include <hip/hip_runtime.h>

typedef unsigned short u16;
typedef unsigned int u32;
typedef __bf16 bf16x8 __attribute__((ext_vector_type(8)));
typedef float f32x4 __attribute__((ext_vector_type(4)));

__device__ __forceinline__ u16 f2bf(float f) {
  u32 u = __builtin_bit_cast(u32, f);
  u = (u + 0x7fffu + ((u >> 16) & 1u)) >> 16;
  return (u16)u;
}
__device__ __forceinline__ float bf2f(u16 h) {
  return __builtin_bit_cast(float, ((u32)h) << 16);
}

// async global->LDS, 16B per lane; LDS dest = wave-uniform base + lane*16 [m97/m104]
__device__ __forceinline__ void gll16(const u16* g, u16* l) {
  __builtin_amdgcn_global_load_lds((const __attribute__((address_space(1))) void*)g,
                                   (__attribute__((address_space(3))) void*)l, 16, 0, 0);
}

// raw barrier: NO implicit vmcnt drain (the whole point of the counted pipeline)
__device__ __forceinline__ void barrier() {
  asm volatile("" ::: "memory");
  __builtin_amdgcn_s_barrier();
  asm volatile("" ::: "memory");
}
__device__ __forceinline__ void waitv8() { asm volatile("s_waitcnt vmcnt(8)" ::: "memory"); }
__device__ __forceinline__ void waitv4() { asm volatile("s_waitcnt vmcnt(4)" ::: "memory"); }
__device__ __forceinline__ void waitv0() { asm volatile("s_waitcnt vmcnt(0)" ::: "memory"); }

// ---------------- all fp32 -> bf16 conversions in one launch ----------------
__global__ __launch_bounds__(256) void cvt_all(const float* __restrict__ x,
                                               const float* __restrict__ WQ,
                                               const float* __restrict__ WK,
                                               const float* __restrict__ WV,
                                               const float* __restrict__ WO,
                                               const float* __restrict__ W1,
                                               const float* __restrict__ W2,
                                               u16* __restrict__ xb,
                                               u16* __restrict__ wqkvb,
                                               u16* __restrict__ wob,
                                               u16* __restrict__ w1b,
                                               u16* __restrict__ w2b) {
  const int S = 1 << 20;
  int i = (blockIdx.x * 256 + threadIdx.x) * 4;
  const float* src;
  u16* dst;
  if (i < 8 * S) { src = x + i; dst = xb + i; }
  else {
    int j = i - 8 * S;
    if (j < 3 * S)      { src = (j < S) ? WQ + j : (j < 2 * S) ? WK + (j - S) : WV + (j - 2 * S);
                          dst = wqkvb + j; }
    else if (j < 4 * S) { src = WO + (j - 3 * S); dst = wob + (j - 3 * S); }
    else if (j < 8 * S) { src = W1 + (j - 4 * S); dst = w1b + (j - 4 * S); }
    else                { src = W2 + (j - 8 * S); dst = w2b + (j - 8 * S); }
  }
  float4 v = *(const float4*)src;
  uint2 o;
  o.x = (u32)f2bf(v.x) | ((u32)f2bf(v.y) << 16);
  o.y = (u32)f2bf(v.z) | ((u32)f2bf(v.w) << 16);
  *(uint2*)dst = o;
}

// ---------------- 256x256 deep-pipelined bf16 MFMA GEMM: C = A @ W^T + bias ----------------
// 512 threads (8 waves, 2M x 4N), BK=32, ring-4 LDS slots (128 KiB total).
// Staging: tile τ's A issued at phase 2τ-6, B at 2τ-5 (prefetch distance 3 tiles);
// steady-state wait = vmcnt(8) once per K-tile (never 0): 8 loads (tiles t+2,t+3)
// stay in flight across barriers [T3+T4]. setprio(1) around each 16-MFMA cluster [T5].
// LDS chunk swizzle: phys chunk = logical ^ ((row>>1)&3), applied on BOTH the
// pre-swizzled global source and the ds_read_b128 side (rule #21) -> conflict-free.
// QKV=1: N=3072 fused; seg0 = Q scaled 0.125*log2(e), seg1=K, seg2=V transposed.
// SPLIT=1: K halved, kz=0 -> C0 (+bias), kz=1 -> C1 (bf16 partials). N=1024 fixed.
template <int RELU, int QKV, int SPLIT>
__global__ __launch_bounds__(512, 2) void gemm256(const u16* __restrict__ A,
                                                  const u16* __restrict__ W,
                                                  const float* __restrict__ bias0,
                                                  void* __restrict__ C0,
                                                  int M, int N, int K,
                                                  const float* __restrict__ bias1,
                                                  void* __restrict__ C1,
                                                  const float* __restrict__ bias2,
                                                  void* __restrict__ C2,
                                                  int NBN) {
  __shared__ alignas(16) u16 lds[4 * 16384];  // 4 slots x (A 256x32 + B 256x32) u16 = 128 KiB
  const int tid = threadIdx.x;
  const int id = blockIdx.x;
  const int xcd = id & 7, r = id >> 3;
  int bm, bn, kz = 0, koff = 0, KL = K;
  if (SPLIT) {
    bn = (r & 3) << 8;            // N = 1024 fixed
    const int q = r >> 2;         // 0..7
    bm = ((q & 3) * 8 + xcd) << 8;
    kz = q >> 2;
    KL = K >> 1;
    koff = kz * KL;
  } else {
    bn = (r % NBN) << 8;
    bm = ((r / NBN) * 8 + xcd) << 8;
  }
  const int wave = tid >> 6, lane = tid & 63;
  const int lr = lane & 15, quad = lane >> 4;
  const int wm = (wave >> 2) << 7;  // 0 or 128
  const int wn = (wave & 3) << 6;   // 0,64,128,192

  // staging: each gll16 call-site = 8 waves x 1KB = one 128-row half of A or B.
  // wave w covers rows w*16..w*16+15 of the half; lane -> (row = lane>>2, phys chunk = lane&3).
  const int lrow = lane >> 2;
  const int lch = (lane & 3) ^ ((lane >> 3) & 3);  // logical chunk for linear phys dest
  const u16* Asrc = A + (size_t)(bm + wave * 16 + lrow) * K + koff + lch * 8;
  const u16* Wsrc = W + (size_t)(bn + wave * 16 + lrow) * K + koff + lch * 8;
  const size_t half = (size_t)128 * K;
  u16* dstbase = lds + wave * 512;  // u16 units; +4096 = second 128-row half

  const int NT = KL >> 5;
  const int fro = (quad ^ ((lr >> 1) & 3)) * 8;  // swizzled ds_read chunk offset (u16)
  f32x4 acc[8][4] = {};

  // prologue: stage tiles 0,1,2 in consumption order (A then B per tile) = 12 loads/wave
  #pragma unroll
  for (int t = 0; t < 3; t++) {
    u16* d = dstbase + t * 16384;
    gll16(Asrc + (size_t)t * 32, d);
    gll16(Asrc + (size_t)t * 32 + half, d + 4096);
    gll16(Wsrc + (size_t)t * 32, d + 8192);
    gll16(Wsrc + (size_t)t * 32 + half, d + 12288);
  }
  waitv8();   // oldest 4 done = tile 0 fully staged; tiles 1,2 in flight
  barrier();

  for (int t = 0; t < NT; t++) {
    const u16* sa = lds + (t & 3) * 16384;
    const u16* sb = sa + 8192;
    const int tp = (t + 3 < NT) ? t + 3 : NT - 1;  // tail: clamp source (junk slot never read)
    u16* d = dstbase + ((t + 3) & 3) * 16384;
    const size_t ko = (size_t)tp * 32;

    // ---- phase 0: quadrant (mi 0..3) ----
    bf16x8 af[4], bfr[4];
    #pragma unroll
    for (int mi = 0; mi < 4; mi++)
      af[mi] = *(const bf16x8*)(sa + (wm + mi * 16 + lr) * 32 + fro);
    #pragma unroll
    for (int ni = 0; ni < 4; ni++)
      bfr[ni] = *(const bf16x8*)(sb + (wn + ni * 16 + lr) * 32 + fro);
    gll16(Asrc + ko, d);              // stage A(t+3)
    gll16(Asrc + ko + half, d + 4096);
    barrier();
    asm volatile("s_waitcnt lgkmcnt(0)" ::: "memory");
    __builtin_amdgcn_s_setprio(1);
    #pragma unroll
    for (int mi = 0; mi < 4; mi++)
      #pragma unroll
      for (int ni = 0; ni < 4; ni++)
        acc[mi][ni] = __builtin_amdgcn_mfma_f32_16x16x32_bf16(af[mi], bfr[ni], acc[mi][ni], 0, 0, 0);
    __builtin_amdgcn_s_setprio(0);
    barrier();

    // ---- phase 1: quadrant (mi 4..7), reuse bfr ----
    #pragma unroll
    for (int mi = 0; mi < 4; mi++)
      af[mi] = *(const bf16x8*)(sa + (wm + 64 + mi * 16 + lr) * 32 + fro);
    gll16(Wsrc + ko, d + 8192);       // stage B(t+3)
    gll16(Wsrc + ko + half, d + 12288);
    barrier();
    asm volatile("s_waitcnt lgkmcnt(0)" ::: "memory");
    __builtin_amdgcn_s_setprio(1);
    #pragma unroll
    for (int mi = 0; mi < 4; mi++)
      #pragma unroll
      for (int ni = 0; ni < 4; ni++)
        acc[4 + mi][ni] = __builtin_amdgcn_mfma_f32_16x16x32_bf16(af[mi], bfr[ni], acc[4 + mi][ni], 0, 0, 0);
    __builtin_amdgcn_s_setprio(0);
    waitv8();   // covers tile t+1 (8 loads of t+2,t+3 remain in flight)
    barrier();
  }
  waitv0();  // drain tail junk loads before LDS dealloc at endpgm

  // epilogue: C/D layout col=lane&15, row=quad*4+reg [m89/m91]
  const float* bp = bias0;
  void* outp = C0;
  float scale = 1.0f;
  int cb = bn, Nout = N, seg = 0;
  if (QKV) {
    Nout = 1024;
    seg = bn >> 10;
    cb = bn & 1023;
    if (seg == 0) scale = 0.125f * 1.44269504089f;  // 1/sqrt(dk) * log2(e): attn uses exp2
    else if (seg == 1) { bp = bias1; outp = C1; }
    else { bp = bias2; outp = C2; }
  }
  if (SPLIT && kz) outp = C1;

  if (QKV && seg == 2) {
    // V: store transposed. 4 consecutive tokens per lane -> 8B packed stores.
    #pragma unroll
    for (int ni = 0; ni < 4; ni++) {
      const int col = cb + wn + ni * 16 + lr;
      const int hh = col >> 6, dl = col & 63;
      const float bv = bp[col];
      #pragma unroll
      for (int mi = 0; mi < 8; mi++) {
        const int row0 = bm + wm + mi * 16 + quad * 4;
        const int bb = row0 >> 11, tt = row0 & 2047;
        u16 pk[4];
        #pragma unroll
        for (int rg = 0; rg < 4; rg++) pk[rg] = f2bf(acc[mi][ni][rg] + bv);
        uint2 val;
        val.x = (u32)pk[0] | ((u32)pk[1] << 16);
        val.y = (u32)pk[2] | ((u32)pk[3] << 16);
        *(uint2*)(((u16*)outp) + ((size_t)((bb * 16 + hh) * 64 + dl)) * 2048 + tt) = val;
      }
    }
    return;
  }

  #pragma unroll
  for (int ni = 0; ni < 4; ni++) {
    const int col = cb + wn + ni * 16 + lr;
    const float bv = (SPLIT && kz) ? 0.0f : bp[col];
    #pragma unroll
    for (int mi = 0; mi < 8; mi++) {
      #pragma unroll
      for (int rg = 0; rg < 4; rg++) {
        int row = bm + wm + mi * 16 + quad * 4 + rg;
        float v = (acc[mi][ni][rg] + bv) * scale;
        if (RELU) v = fmaxf(v, 0.0f);
        ((u16*)outp)[(size_t)row * Nout + col] = f2bf(v);
      }
    }
  }
}

// ---------------- MFMA flash attention: shared k-sweep, S^T layout ----------------
// Block p handles q-tiles A=31-p and B=p with one k-sweep; K/V staged once.
// K/V double-buffered (ring-2) with counted vmcnt [T3/T4 port]: per iter
// {barrier; STAGE(kt+1)->slot (kt+1)&1; vmcnt(4); barrier; compute(kt)} —
// each wave stages its own 16 rows, so vmcnt(4)+barrier == "tile kt staged by
// ALL waves"; kt+1's 4 loads stay in flight across the whole compute (never 0).
// S^T = K Q^T via mfma(kf, qf): each lane then holds 16 P values for ITS query
// (query=lr, keys=nt*16+quad*4+rg) -> packed b64 P writes (v_perm pairs) and
// register row-sums for the denominator (no ones-MFMA, no shuffle per tile).
// Scores pre-scaled by log2(e)/8 -> P = exp2(s); mask -1e30 underflows to 0.
constexpr int ALD = 72;  // sP row stride (u16)

__global__ __launch_bounds__(256) void attn_mfma(const u16* __restrict__ qb,
                                                 const u16* __restrict__ kb,
                                                 const u16* __restrict__ vt,
                                                 u16* __restrict__ ctxb, int T) {
  __shared__ alignas(16) u16 sK[2][64 * 64];
  __shared__ alignas(16) u16 sVt[2][64 * 64];
  __shared__ alignas(16) u16 sP[4 * 2 * 16 * ALD];
  const int tid = threadIdx.x;
  const int i = blockIdx.x;
  const int g = (i & 7) | (((i >> 7) & 7) << 3);  // all 16 p-blocks of g share i&7 (XCD)
  const int p = (i >> 3) & 15;
  const int h = g >> 2, b = g & 3;
  const size_t base = ((size_t)(b * T)) * 1024 + h * 64;
  const size_t vbase = ((size_t)((b * 16 + h) * 64)) * T;
  const int lane = tid & 63, wave = tid >> 6;
  const int lr = lane & 15, quad = lane >> 4;
  u16* sPA = sP + (wave * 2) * 16 * ALD;
  u16* sPB = sPA + 16 * ALD;

  const int srow = lane >> 3;
  const int sch = ((lane & 7) ^ srow) * 8;
  const int fsw = lr & 7;

  const int qtA = 31 - p, qtB = p;

  // stage tile ktt's K/V into slot; clamp past-end sources (junk slot never read)
#define STAGEKV(ktt, slot) {                                                       \
    const int kc_ = ((ktt) <= qtA) ? (ktt) : qtA;                                  \
    _Pragma("unroll") for (int j_ = 0; j_ < 2; j_++) {                             \
      const int rb_ = (wave * 2 + j_) * 8;                                         \
      const int rr_ = rb_ + srow;                                                  \
      gll16(kb + base + (size_t)(kc_ * 64 + rr_) * 1024 + sch, sK[slot] + rb_ * 64);\
      gll16(vt + vbase + (size_t)rr_ * T + (size_t)(kc_ * 64) + sch, sVt[slot] + rb_ * 64);\
    } }

  const int q0A = qtA * 64 + wave * 16, q0B = qtB * 64 + wave * 16;
  bf16x8 qfA[2], qfB[2];
  #pragma unroll
  for (int sl = 0; sl < 2; sl++) {
    uint4 uA = *(const uint4*)(qb + base + (size_t)(q0A + lr) * 1024 + sl * 32 + quad * 8);
    qfA[sl] = __builtin_bit_cast(bf16x8, uA);
    uint4 uB = *(const uint4*)(qb + base + (size_t)(q0B + lr) * 1024 + sl * 32 + quad * 8);
    qfB[sl] = __builtin_bit_cast(bf16x8, uB);
  }
  f32x4 oA[4] = {}, oB[4] = {};
  float smA[4] = {0, 0, 0, 0}, smB[4] = {0, 0, 0, 0};

  STAGEKV(0, 0);  // prologue: tile 0 in flight

  for (int kt = 0; kt <= qtA; kt++) {
    const bool doB = (kt <= qtB);
    barrier();                      // all waves done reading slot (kt+1)&1 (iter kt-1)
    STAGEKV(kt + 1, (kt + 1) & 1);  // prefetch next tile (4 loads/wave, in flight)
    waitv4();                       // this wave's tile-kt loads landed
    barrier();                      // => ALL waves' tile-kt loads landed
    const u16* sKc = sK[kt & 1];
    const u16* sVc = sVt[kt & 1];

    // S^T = K Q^T (kf as A operand, shared between q-tiles); log2 units.
    // D: col=lane&15 -> query=lr, row=quad*4+rg -> key nt*16+quad*4+rg.
    f32x4 sa[4] = {}, sb[4] = {};
    #pragma unroll
    for (int sl = 0; sl < 2; sl++) {
      bf16x8 kf[4];
      #pragma unroll
      for (int nt = 0; nt < 4; nt++)
        kf[nt] = *(const bf16x8*)(sKc + (nt * 16 + lr) * 64 + ((((sl << 2) | quad) ^ fsw) * 8));
      #pragma unroll
      for (int nt = 0; nt < 4; nt++)
        sa[nt] = __builtin_amdgcn_mfma_f32_16x16x32_bf16(kf[nt], qfA[sl], sa[nt], 0, 0, 0);
      if (doB) {
        #pragma unroll
        for (int nt = 0; nt < 4; nt++)
          sb[nt] = __builtin_amdgcn_mfma_f32_16x16x32_bf16(kf[nt], qfB[sl], sb[nt], 0, 0, 0);
      }
    }

    // causal masks on diagonal tiles: key (nt*16+quad*4+rg) > query (wave*16+lr)
    const int qloc = wave * 16 + lr;
    if (kt == qtA) {
      #pragma unroll
      for (int nt = 0; nt < 4; nt++)
        #pragma unroll
        for (int rg = 0; rg < 4; rg++)
          if (nt * 16 + quad * 4 + rg > qloc) sa[nt][rg] = -1e30f;
    }
    if (doB && kt == qtB) {
      #pragma unroll
      for (int nt = 0; nt < 4; nt++)
        #pragma unroll
        for (int rg = 0; rg < 4; rg++)
          if (nt * 16 + quad * 4 + rg > qloc) sb[nt][rg] = -1e30f;
    }

    // P = exp2(S), v_perm-packed truncated bf16, one b64 write per nt;
    // row-sum accumulated in registers (lane's own query).
    #pragma unroll
    for (int nt = 0; nt < 4; nt++) {
      float e0 = __builtin_amdgcn_exp2f(sa[nt][0]);
      float e1 = __builtin_amdgcn_exp2f(sa[nt][1]);
      float e2 = __builtin_amdgcn_exp2f(sa[nt][2]);
      float e3 = __builtin_amdgcn_exp2f(sa[nt][3]);
      smA[nt] += (e0 + e1) + (e2 + e3);
      uint2 pk;
      pk.x = __builtin_amdgcn_perm(__builtin_bit_cast(u32, e1), __builtin_bit_cast(u32, e0), 0x07060302u);
      pk.y = __builtin_amdgcn_perm(__builtin_bit_cast(u32, e3), __builtin_bit_cast(u32, e2), 0x07060302u);
      *(uint2*)(sPA + lr * ALD + nt * 16 + quad * 4) = pk;
    }
    if (doB) {
      #pragma unroll
      for (int nt = 0; nt < 4; nt++) {
        float e0 = __builtin_amdgcn_exp2f(sb[nt][0]);
        float e1 = __builtin_amdgcn_exp2f(sb[nt][1]);
        float e2 = __builtin_amdgcn_exp2f(sb[nt][2]);
        float e3 = __builtin_amdgcn_exp2f(sb[nt][3]);
        smB[nt] += (e0 + e1) + (e2 + e3);
        uint2 pk;
        pk.x = __builtin_amdgcn_perm(__builtin_bit_cast(u32, e1), __builtin_bit_cast(u32, e0), 0x07060302u);
        pk.y = __builtin_amdgcn_perm(__builtin_bit_cast(u32, e3), __builtin_bit_cast(u32, e2), 0x07060302u);
        *(uint2*)(sPB + lr * ALD + nt * 16 + quad * 4) = pk;
      }
    }
    asm volatile("" ::: "memory");  // wave-private: per-wave DS ordering suffices

    // O += P V  (vf shared between q-tiles)
    #pragma unroll
    for (int sl = 0; sl < 2; sl++) {
      bf16x8 vf[4];
      #pragma unroll
      for (int nt = 0; nt < 4; nt++)
        vf[nt] = *(const bf16x8*)(sVc + (nt * 16 + lr) * 64 + ((((sl << 2) | quad) ^ fsw) * 8));
      bf16x8 pfA = *(const bf16x8*)(sPA + lr * ALD + sl * 32 + quad * 8);
      #pragma unroll
      for (int nt = 0; nt < 4; nt++)
        oA[nt] = __builtin_amdgcn_mfma_f32_16x16x32_bf16(pfA, vf[nt], oA[nt], 0, 0, 0);
      if (doB) {
        bf16x8 pfB = *(const bf16x8*)(sPB + lr * ALD + sl * 32 + quad * 8);
        #pragma unroll
        for (int nt = 0; nt < 4; nt++)
          oB[nt] = __builtin_amdgcn_mfma_f32_16x16x32_bf16(pfB, vf[nt], oB[nt], 0, 0, 0);
      }
    }
  }
  waitv0();  // drain tail junk loads before LDS dealloc at endpgm
#undef STAGEKV

  // denominators: lane holds l for query=lr (4 partials); reduce across quads,
  // then shfl to the (quad*4+rg) distribution the C-layout epilogue needs.
  float sumA = (smA[0] + smA[1]) + (smA[2] + smA[3]);
  sumA += __shfl_xor(sumA, 16);
  sumA += __shfl_xor(sumA, 32);
  float sumB = (smB[0] + smB[1]) + (smB[2] + smB[3]);
  sumB += __shfl_xor(sumB, 16);
  sumB += __shfl_xor(sumB, 32);
  float invA[4], invB[4];
  #pragma unroll
  for (int rg = 0; rg < 4; rg++) {
    invA[rg] = 1.0f / __shfl(sumA, quad * 4 + rg);
    invB[rg] = 1.0f / __shfl(sumB, quad * 4 + rg);
  }
  #pragma unroll
  for (int nt = 0; nt < 4; nt++)
    #pragma unroll
    for (int rg = 0; rg < 4; rg++) {
      int qrow = q0A + quad * 4 + rg;
      ctxb[base + (size_t)qrow * 1024 + nt * 16 + lr] = f2bf(oA[nt][rg] * invA[rg]);
    }
  #pragma unroll
  for (int nt = 0; nt < 4; nt++)
    #pragma unroll
    for (int rg = 0; rg < 4; rg++) {
      int qrow = q0B + quad * 4 + rg;
      ctxb[base + (size_t)qrow * 1024 + nt * 16 + lr] = f2bf(oB[nt][rg] * invB[rg]);
    }
}

// ---------------- fused residual + split-K reduce (bf16 partials) + LayerNorm ----------------
// out = LN(a + b + c) * g + be ;  a is fp32 (ABF=0) or bf16 (ABF=1); b,c bf16 partials
template <int ABF>
__global__ __launch_bounds__(256) void ln_kernel(const void* __restrict__ a,
                                                 const u16* __restrict__ b,
                                                 const u16* __restrict__ c,
                                                 const float* __restrict__ g,
                                                 const float* __restrict__ be,
                                                 float* __restrict__ of32,
                                                 u16* __restrict__ obf) {
  const int row = blockIdx.x;
  const int tid = threadIdx.x;
  const size_t base = (size_t)row * 1024;
  const int cc = tid * 4;
  float a0, a1, a2, a3;
  if (ABF) {
    uint2 ua = *(const uint2*)((const u16*)a + base + cc);
    a0 = bf2f(ua.x & 0xffff); a1 = bf2f(ua.x >> 16);
    a2 = bf2f(ua.y & 0xffff); a3 = bf2f(ua.y >> 16);
  } else {
    float4 xa = *(const float4*)((const float*)a + base + cc);
    a0 = xa.x; a1 = xa.y; a2 = xa.z; a3 = xa.w;
  }
  uint2 ub = *(const uint2*)(b + base + cc);
  uint2 uc = *(const uint2*)(c + base + cc);
  float v0 = a0 + bf2f(ub.x & 0xffff) + bf2f(uc.x & 0xffff);
  float v1 = a1 + bf2f(ub.x >> 16)    + bf2f(uc.x >> 16);
  float v2 = a2 + bf2f(ub.y & 0xffff) + bf2f(uc.y & 0xffff);
  float v3 = a3 + bf2f(ub.y >> 16)    + bf2f(uc.y >> 16);
  float s1 = v0 + v1 + v2 + v3;
  float s2 = v0 * v0 + v1 * v1 + v2 * v2 + v3 * v3;
  for (int off = 1; off < 64; off <<= 1) {
    s1 += __shfl_xor(s1, off);
    s2 += __shfl_xor(s2, off);
  }
  __shared__ float red[8];
  int wv = tid >> 6;
  if ((tid & 63) == 0) { red[wv] = s1; red[4 + wv] = s2; }
  __syncthreads();
  s1 = red[0] + red[1] + red[2] + red[3];
  s2 = red[4] + red[5] + red[6] + red[7];
  float mu = s1 * (1.0f / 1024.0f);
  float var = s2 * (1.0f / 1024.0f) - mu * mu;
  float rs = rsqrtf(var + 1e-5f);
  float4 gv = *(const float4*)(g + cc);
  float4 bev = *(const float4*)(be + cc);
  float y0 = (v0 - mu) * rs * gv.x + bev.x;
  float y1 = (v1 - mu) * rs * gv.y + bev.y;
  float y2 = (v2 - mu) * rs * gv.z + bev.z;
  float y3 = (v3 - mu) * rs * gv.w + bev.w;
  if (of32) {
    float4 o = make_float4(y0, y1, y2, y3);
    *(float4*)(of32 + base + cc) = o;
  }
  if (obf) {
    uint2 o;
    o.x = (u32)f2bf(y0) | ((u32)f2bf(y1) << 16);
    o.y = (u32)f2bf(y2) | ((u32)f2bf(y3) << 16);
    *(uint2*)(obf + base + cc) = o;
  }
}

// ---------------- launch ----------------
extern "C" void kernel_launch(void* const* d_in, const int* in_sizes, int n_in,
                              void* d_out, int out_size, void* d_ws, size_t ws_size,
                              hipStream_t stream) {
  const int Mtok = 8192, D = 1024, F = 4096, T = 2048;
  const float* x   = (const float*)d_in[0];
  const float* WQ  = (const float*)d_in[1];
  const float* bQ  = (const float*)d_in[2];
  const float* WK  = (const float*)d_in[3];
  const float* bK  = (const float*)d_in[4];
  const float* WV  = (const float*)d_in[5];
  const float* bV  = (const float*)d_in[6];
  const float* WO  = (const float*)d_in[7];
  const float* bO  = (const float*)d_in[8];
  const float* W1  = (const float*)d_in[9];
  const float* b1  = (const float*)d_in[10];
  const float* W2  = (const float*)d_in[11];
  const float* b2  = (const float*)d_in[12];
  const float* g1  = (const float*)d_in[13];
  const float* be1 = (const float*)d_in[14];
  const float* g2  = (const float*)d_in[15];
  const float* be2 = (const float*)d_in[16];

  char* ws = (char*)d_ws;
  const size_t MB = 1024 * 1024;
  u16*  xb     = (u16*)(ws + 0);          // 16 MB (dead after QKV)
  u16*  wqkvb  = (u16*)(ws + 16 * MB);    // 6 MB  (dead after QKV)
  u16*  wob    = (u16*)(ws + 22 * MB);    // 2 MB  (dead after WO)
  u16*  w1b    = (u16*)(ws + 24 * MB);    // 8 MB  (dead after FF1)
  u16*  w2b    = (u16*)(ws + 32 * MB);    // 8 MB  (dead after FF2)
  u16*  qb     = (u16*)(ws + 40 * MB);    // 16 MB (dead after attn)
  u16*  kb     = (u16*)(ws + 56 * MB);    // 16 MB (dead after attn)
  u16*  vtb    = (u16*)(ws + 72 * MB);    // 16 MB, written transposed by QKV (dead after attn)
  u16*  ctxb   = (u16*)(ws + 88 * MB);    // 16 MB (dead after WO)
  u16*  wp0    = (u16*)(ws + 104 * MB);   // 16 MB bf16 partial (dead after ln1)
  u16*  wp1    = (u16*)(ws + 120 * MB);   // 16 MB bf16 partial (dead after ln1)
  u16*  h1b    = (u16*)(ws + 136 * MB);   // 16 MB bf16 LN1 output (live until ln2)
  u16*  ff1b   = (u16*)(ws + 40 * MB);    // 64 MB over qb..ctxb (dead after FF2)
  u16*  fp0    = (u16*)(ws + 0);          // 16 MB bf16 partial over xb
  u16*  fp1    = (u16*)(ws + 16 * MB);    // 16 MB bf16 partial over wqkvb/wob
  float* out   = (float*)d_out;

  dim3 blk(256);
  dim3 blk512(512);
  cvt_all<<<(20 << 20) / 1024, blk, 0, stream>>>(x, WQ, WK, WV, WO, W1, W2,
                                                 xb, wqkvb, wob, w1b, w2b);

  // fused QKV (N=3072): seg0=Q scaled log2(e)/8, seg1=K, seg2=V stored transposed
  gemm256<0, 1, 0><<<dim3(384), blk512, 0, stream>>>(xb, wqkvb, bQ, qb, Mtok, 3072, D,
                                                     bK, kb, bV, vtb, 12);
  attn_mfma<<<dim3(1024), blk, 0, stream>>>(qb, kb, vtb, ctxb, T);

  // WO projection, split-K=2 -> bf16 partials wp0/wp1; ln1 reduces
  gemm256<0, 0, 1><<<dim3(256), blk512, 0, stream>>>(ctxb, wob, bO, wp0, Mtok, D, D,
                                                     nullptr, wp1, nullptr, nullptr, 4);
  ln_kernel<0><<<Mtok, blk, 0, stream>>>(x, wp0, wp1, g1, be1, nullptr, h1b);

  gemm256<1, 0, 0><<<dim3(512), blk512, 0, stream>>>(h1b, w1b, b1, ff1b, Mtok, F, D,
                                                     nullptr, nullptr, nullptr, nullptr, 16);
  // FF2, split-K=2 -> bf16 partials fp0/fp1; ln2 reduces (bf16 residual h1b)
  gemm256<0, 0, 1><<<dim3(256), blk512, 0, stream>>>(ff1b, w2b, b2, fp0, Mtok, D, F,
                                                     nullptr, fp1, nullptr, nullptr, 4);
  ln_kernel<1><<<Mtok, blk, 0, stream>>>(h1b, fp0, fp1, g2, be2, out, (u16*)nullptr);
}

// Round 4
// 503.880 us; speedup vs baseline: 1.0182x; 1.0017x over previous
//
#include <hip/hip_runtime.h>

typedef unsigned short u16;
typedef unsigned int u32;
typedef __bf16 bf16x8 __attribute__((ext_vector_type(8)));
typedef float f32x4 __attribute__((ext_vector_type(4)));
typedef float f32x16 __attribute__((ext_vector_type(16)));

__device__ __forceinline__ u16 f2bf(float f) {
  u32 u = __builtin_bit_cast(u32, f);
  u = (u + 0x7fffu + ((u >> 16) & 1u)) >> 16;
  return (u16)u;
}
__device__ __forceinline__ float bf2f(u16 h) {
  return __builtin_bit_cast(float, ((u32)h) << 16);
}

// async global->LDS, 16B per lane; LDS dest = wave-uniform base + lane*16 [m97/m104]
__device__ __forceinline__ void gll16(const u16* g, u16* l) {
  __builtin_amdgcn_global_load_lds((const __attribute__((address_space(1))) void*)g,
                                   (__attribute__((address_space(3))) void*)l, 16, 0, 0);
}

// raw barrier: NO implicit vmcnt drain (the whole point of the counted pipeline)
__device__ __forceinline__ void barrier() {
  asm volatile("" ::: "memory");
  __builtin_amdgcn_s_barrier();
  asm volatile("" ::: "memory");
}
__device__ __forceinline__ void waitv8() { asm volatile("s_waitcnt vmcnt(8)" ::: "memory"); }
__device__ __forceinline__ void waitv4() { asm volatile("s_waitcnt vmcnt(4)" ::: "memory"); }
__device__ __forceinline__ void waitv0() { asm volatile("s_waitcnt vmcnt(0)" ::: "memory"); }

// ---------------- all fp32 -> bf16 conversions in one launch ----------------
__global__ __launch_bounds__(256) void cvt_all(const float* __restrict__ x,
                                               const float* __restrict__ WQ,
                                               const float* __restrict__ WK,
                                               const float* __restrict__ WV,
                                               const float* __restrict__ WO,
                                               const float* __restrict__ W1,
                                               const float* __restrict__ W2,
                                               u16* __restrict__ xb,
                                               u16* __restrict__ wqkvb,
                                               u16* __restrict__ wob,
                                               u16* __restrict__ w1b,
                                               u16* __restrict__ w2b) {
  const int S = 1 << 20;
  int i = (blockIdx.x * 256 + threadIdx.x) * 4;
  const float* src;
  u16* dst;
  if (i < 8 * S) { src = x + i; dst = xb + i; }
  else {
    int j = i - 8 * S;
    if (j < 3 * S)      { src = (j < S) ? WQ + j : (j < 2 * S) ? WK + (j - S) : WV + (j - 2 * S);
                          dst = wqkvb + j; }
    else if (j < 4 * S) { src = WO + (j - 3 * S); dst = wob + (j - 3 * S); }
    else if (j < 8 * S) { src = W1 + (j - 4 * S); dst = w1b + (j - 4 * S); }
    else                { src = W2 + (j - 8 * S); dst = w2b + (j - 8 * S); }
  }
  float4 v = *(const float4*)src;
  uint2 o;
  o.x = (u32)f2bf(v.x) | ((u32)f2bf(v.y) << 16);
  o.y = (u32)f2bf(v.z) | ((u32)f2bf(v.w) << 16);
  *(uint2*)dst = o;
}

// ---------------- 256x256 deep-pipelined bf16 MFMA GEMM: C = A @ W^T + bias ----------------
// 512 threads (8 waves, 2M x 4N), BK=32, ring-4 LDS slots (128 KiB total).
// Staging: tile τ's A issued at phase 2τ-6, B at 2τ-5 (prefetch distance 3 tiles);
// steady-state wait = vmcnt(8) once per K-tile (never 0): 8 loads (tiles t+2,t+3)
// stay in flight across barriers [T3+T4]. setprio(1) around each 16-MFMA cluster [T5].
// LDS chunk swizzle applied on BOTH source and ds_read side (rule #21) -> conflict-free.
// QKV=1: N=3072 fused; seg0 = Q scaled 0.125*log2(e), seg1=K, seg2=V transposed.
// SPLIT=1: K halved, kz=0 -> C0 (+bias), kz=1 -> C1 (bf16 partials). N=1024 fixed.
template <int RELU, int QKV, int SPLIT>
__global__ __launch_bounds__(512, 2) void gemm256(const u16* __restrict__ A,
                                                  const u16* __restrict__ W,
                                                  const float* __restrict__ bias0,
                                                  void* __restrict__ C0,
                                                  int M, int N, int K,
                                                  const float* __restrict__ bias1,
                                                  void* __restrict__ C1,
                                                  const float* __restrict__ bias2,
                                                  void* __restrict__ C2,
                                                  int NBN) {
  __shared__ alignas(16) u16 lds[4 * 16384];  // 4 slots x (A 256x32 + B 256x32) u16 = 128 KiB
  const int tid = threadIdx.x;
  const int id = blockIdx.x;
  const int xcd = id & 7, r = id >> 3;
  int bm, bn, kz = 0, koff = 0, KL = K;
  if (SPLIT) {
    bn = (r & 3) << 8;            // N = 1024 fixed
    const int q = r >> 2;         // 0..7
    bm = ((q & 3) * 8 + xcd) << 8;
    kz = q >> 2;
    KL = K >> 1;
    koff = kz * KL;
  } else {
    bn = (r % NBN) << 8;
    bm = ((r / NBN) * 8 + xcd) << 8;
  }
  const int wave = tid >> 6, lane = tid & 63;
  const int lr = lane & 15, quad = lane >> 4;
  const int wm = (wave >> 2) << 7;  // 0 or 128
  const int wn = (wave & 3) << 6;   // 0,64,128,192

  // staging: each gll16 call-site = 8 waves x 1KB = one 128-row half of A or B.
  // wave w covers rows w*16..w*16+15 of the half; lane -> (row = lane>>2, phys chunk = lane&3).
  const int lrow = lane >> 2;
  const int lch = (lane & 3) ^ ((lane >> 3) & 3);  // logical chunk for linear phys dest
  const u16* Asrc = A + (size_t)(bm + wave * 16 + lrow) * K + koff + lch * 8;
  const u16* Wsrc = W + (size_t)(bn + wave * 16 + lrow) * K + koff + lch * 8;
  const size_t half = (size_t)128 * K;
  u16* dstbase = lds + wave * 512;  // u16 units; +4096 = second 128-row half

  const int NT = KL >> 5;
  const int fro = (quad ^ ((lr >> 1) & 3)) * 8;  // swizzled ds_read chunk offset (u16)
  f32x4 acc[8][4] = {};

  // prologue: stage tiles 0,1,2 in consumption order (A then B per tile) = 12 loads/wave
  #pragma unroll
  for (int t = 0; t < 3; t++) {
    u16* d = dstbase + t * 16384;
    gll16(Asrc + (size_t)t * 32, d);
    gll16(Asrc + (size_t)t * 32 + half, d + 4096);
    gll16(Wsrc + (size_t)t * 32, d + 8192);
    gll16(Wsrc + (size_t)t * 32 + half, d + 12288);
  }
  waitv8();   // oldest 4 done = tile 0 fully staged; tiles 1,2 in flight
  barrier();

  for (int t = 0; t < NT; t++) {
    const u16* sa = lds + (t & 3) * 16384;
    const u16* sb = sa + 8192;
    const int tp = (t + 3 < NT) ? t + 3 : NT - 1;  // tail: clamp source (junk slot never read)
    u16* d = dstbase + ((t + 3) & 3) * 16384;
    const size_t ko = (size_t)tp * 32;

    // ---- phase 0: quadrant (mi 0..3) ----
    bf16x8 af[4], bfr[4];
    #pragma unroll
    for (int mi = 0; mi < 4; mi++)
      af[mi] = *(const bf16x8*)(sa + (wm + mi * 16 + lr) * 32 + fro);
    #pragma unroll
    for (int ni = 0; ni < 4; ni++)
      bfr[ni] = *(const bf16x8*)(sb + (wn + ni * 16 + lr) * 32 + fro);
    gll16(Asrc + ko, d);              // stage A(t+3)
    gll16(Asrc + ko + half, d + 4096);
    barrier();
    asm volatile("s_waitcnt lgkmcnt(0)" ::: "memory");
    __builtin_amdgcn_s_setprio(1);
    #pragma unroll
    for (int mi = 0; mi < 4; mi++)
      #pragma unroll
      for (int ni = 0; ni < 4; ni++)
        acc[mi][ni] = __builtin_amdgcn_mfma_f32_16x16x32_bf16(af[mi], bfr[ni], acc[mi][ni], 0, 0, 0);
    __builtin_amdgcn_s_setprio(0);
    barrier();

    // ---- phase 1: quadrant (mi 4..7), reuse bfr ----
    #pragma unroll
    for (int mi = 0; mi < 4; mi++)
      af[mi] = *(const bf16x8*)(sa + (wm + 64 + mi * 16 + lr) * 32 + fro);
    gll16(Wsrc + ko, d + 8192);       // stage B(t+3)
    gll16(Wsrc + ko + half, d + 12288);
    barrier();
    asm volatile("s_waitcnt lgkmcnt(0)" ::: "memory");
    __builtin_amdgcn_s_setprio(1);
    #pragma unroll
    for (int mi = 0; mi < 4; mi++)
      #pragma unroll
      for (int ni = 0; ni < 4; ni++)
        acc[4 + mi][ni] = __builtin_amdgcn_mfma_f32_16x16x32_bf16(af[mi], bfr[ni], acc[4 + mi][ni], 0, 0, 0);
    __builtin_amdgcn_s_setprio(0);
    waitv8();   // covers tile t+1 (8 loads of t+2,t+3 remain in flight)
    barrier();
  }
  waitv0();  // drain tail junk loads before LDS dealloc at endpgm

  // epilogue: C/D layout col=lane&15, row=quad*4+reg [m89/m91]
  const float* bp = bias0;
  void* outp = C0;
  float scale = 1.0f;
  int cb = bn, Nout = N, seg = 0;
  if (QKV) {
    Nout = 1024;
    seg = bn >> 10;
    cb = bn & 1023;
    if (seg == 0) scale = 0.125f * 1.44269504089f;  // 1/sqrt(dk) * log2(e): attn uses exp2
    else if (seg == 1) { bp = bias1; outp = C1; }
    else { bp = bias2; outp = C2; }
  }
  if (SPLIT && kz) outp = C1;

  if (QKV && seg == 2) {
    // V: store transposed. 4 consecutive tokens per lane -> 8B packed stores.
    #pragma unroll
    for (int ni = 0; ni < 4; ni++) {
      const int col = cb + wn + ni * 16 + lr;
      const int hh = col >> 6, dl = col & 63;
      const float bv = bp[col];
      #pragma unroll
      for (int mi = 0; mi < 8; mi++) {
        const int row0 = bm + wm + mi * 16 + quad * 4;
        const int bb = row0 >> 11, tt = row0 & 2047;
        u16 pk[4];
        #pragma unroll
        for (int rg = 0; rg < 4; rg++) pk[rg] = f2bf(acc[mi][ni][rg] + bv);
        uint2 val;
        val.x = (u32)pk[0] | ((u32)pk[1] << 16);
        val.y = (u32)pk[2] | ((u32)pk[3] << 16);
        *(uint2*)(((u16*)outp) + ((size_t)((bb * 16 + hh) * 64 + dl)) * 2048 + tt) = val;
      }
    }
    return;
  }

  #pragma unroll
  for (int ni = 0; ni < 4; ni++) {
    const int col = cb + wn + ni * 16 + lr;
    const float bv = (SPLIT && kz) ? 0.0f : bp[col];
    #pragma unroll
    for (int mi = 0; mi < 8; mi++) {
      #pragma unroll
      for (int rg = 0; rg < 4; rg++) {
        int row = bm + wm + mi * 16 + quad * 4 + rg;
        float v = (acc[mi][ni][rg] + bv) * scale;
        if (RELU) v = fmaxf(v, 0.0f);
        ((u16*)outp)[(size_t)row * Nout + col] = f2bf(v);
      }
    }
  }
}

// ---------------- MFMA flash attention: 32x32 S^T, in-register softmax [m214/T12] ----------------
// Block p handles q-tiles A=31-p and B=p with one k-sweep; each of the 4 waves owns a
// 32-query sub-tile (roles rotated by blockIdx for SIMD balance). K/V double-buffered
// (ring-2) with counted vmcnt [T3/T4]: {barrier; STAGE(kt+1); vmcnt(4); barrier; compute}.
// S^T = K Q^T via mfma_32x32x16(kf, qf): D col=lane&31=query, row=(reg&3)+8*(reg>>2)+4*(lane>>5)=key
// [m74/m101]. Softmax fully in-register: P=exp2(S) (Q pre-scaled log2(e)/8), truncated-bf16
// v_perm packs + ONE v_permlane32_swap per word-pair build the PV A-fragment (keys
// hh*8+0..7 per lane) with NO LDS round-trip. Row-sum = in-lane + one shfl_xor(32).
__global__ __launch_bounds__(256) void attn_mfma(const u16* __restrict__ qb,
                                                 const u16* __restrict__ kb,
                                                 const u16* __restrict__ vt,
                                                 u16* __restrict__ ctxb, int T) {
  __shared__ alignas(16) u16 sK[2][64 * 64];
  __shared__ alignas(16) u16 sVt[2][64 * 64];
  const int tid = threadIdx.x;
  const int i = blockIdx.x;
  const int g = (i & 7) | (((i >> 7) & 7) << 3);  // all 16 p-blocks of g share i&7 (XCD)
  const int p = (i >> 3) & 15;
  const int h = g >> 2, b = g & 3;
  const size_t base = ((size_t)(b * T)) * 1024 + h * 64;
  const size_t vbase = ((size_t)((b * 16 + h) * 64)) * T;
  const int lane = tid & 63, wave = tid >> 6;
  const int l31 = lane & 31, hh = lane >> 5;

  const int srow = lane >> 3;
  const int sch = ((lane & 7) ^ srow) * 8;

  const int qtA = 31 - p, qtB = p;
  const int vw = (wave + (i & 3)) & 3;         // rotate roles across blocks: SIMD balance
  const int myqt = (vw >> 1) ? qtB : qtA;
  const int q0w = myqt * 64 + (vw & 1) * 32;   // this wave's 32-query block

  // stage tile ktt's K/V into slot; clamp past-end sources (junk slot never read)
#define STAGEKV(ktt, slot) {                                                       \
    const int kc_ = ((ktt) <= qtA) ? (ktt) : qtA;                                  \
    _Pragma("unroll") for (int j_ = 0; j_ < 2; j_++) {                             \
      const int rb_ = (wave * 2 + j_) * 8;                                         \
      const int rr_ = rb_ + srow;                                                  \
      gll16(kb + base + (size_t)(kc_ * 64 + rr_) * 1024 + sch, sK[slot] + rb_ * 64);\
      gll16(vt + vbase + (size_t)rr_ * T + (size_t)(kc_ * 64) + sch, sVt[slot] + rb_ * 64);\
    } }

  // Q fragments (B-operand): lane holds Q[q0w+l31][ds*16 + hh*8 + 0..7]
  bf16x8 qf[4];
  #pragma unroll
  for (int ds = 0; ds < 4; ds++) {
    uint4 uq = *(const uint4*)(qb + base + (size_t)(q0w + l31) * 1024 + ds * 16 + hh * 8);
    qf[ds] = __builtin_bit_cast(bf16x8, uq);
  }
  f32x16 o0 = {}, o1 = {};
  float rsum = 0.0f;
  const int fs8 = (l31 & 7);

  STAGEKV(0, 0);  // prologue: tile 0 in flight

  for (int kt = 0; kt <= qtA; kt++) {
    barrier();                      // all waves done reading slot (kt+1)&1 (iter kt-1)
    STAGEKV(kt + 1, (kt + 1) & 1);  // prefetch next tile (4 loads/wave, in flight)
    waitv4();                       // this wave's tile-kt loads landed
    barrier();                      // => ALL waves' tile-kt loads landed
    if (kt <= myqt) {
      const u16* sKc = sK[kt & 1];
      const u16* sVc = sVt[kt & 1];

      // S^T = K Q^T: s0 = keys kt*64+0..31, s1 = +32..63 (row-split by hh)
      f32x16 s0v = {}, s1v = {};
      #pragma unroll
      for (int ds = 0; ds < 4; ds++) {
        const int co = ((2 * ds + hh) ^ fs8) * 8;
        bf16x8 kf0 = *(const bf16x8*)(sKc + l31 * 64 + co);
        bf16x8 kf1 = *(const bf16x8*)(sKc + (32 + l31) * 64 + co);
        s0v = __builtin_amdgcn_mfma_f32_32x32x16_bf16(kf0, qf[ds], s0v, 0, 0, 0);
        s1v = __builtin_amdgcn_mfma_f32_32x32x16_bf16(kf1, qf[ds], s1v, 0, 0, 0);
      }

      // causal mask on this wave's diagonal tile
      if (kt == myqt) {
        const int qloc = ((vw & 1) << 5) + l31;
        #pragma unroll
        for (int rg = 0; rg < 16; rg++) {
          const int key = (rg & 3) + 8 * (rg >> 2) + 4 * hh;
          if (key > qloc) s0v[rg] = -1e30f;
          if (key + 32 > qloc) s1v[rg] = -1e30f;
        }
      }

      // P = exp2(S) in-register; row-sum per lane (its own query)
      float e[32];
      #pragma unroll
      for (int rg = 0; rg < 16; rg++) {
        e[rg] = __builtin_amdgcn_exp2f(s0v[rg]);
        e[16 + rg] = __builtin_amdgcn_exp2f(s1v[rg]);
        rsum += e[rg] + e[16 + rg];
      }

      // pack to PV A-fragments: pf[s] = P[q=l31][keys 16s + hh*8 + 0..7].
      // word pairing: swap(pk(e0,e1), pk(e4,e5)) -> {w0, w2}; swap(pk(e2,e3), pk(e6,e7)) -> {w1, w3}.
      union PW { u32 w[4]; bf16x8 v; } pf[4];
      #pragma unroll
      for (int t = 0; t < 2; t++) {
        #pragma unroll
        for (int sl = 0; sl < 2; sl++) {
          const int rb = t * 16 + sl * 8;
          u32 wa = __builtin_amdgcn_perm(__builtin_bit_cast(u32, e[rb + 1]), __builtin_bit_cast(u32, e[rb + 0]), 0x07060302u);
          u32 wb = __builtin_amdgcn_perm(__builtin_bit_cast(u32, e[rb + 5]), __builtin_bit_cast(u32, e[rb + 4]), 0x07060302u);
          u32 wc = __builtin_amdgcn_perm(__builtin_bit_cast(u32, e[rb + 3]), __builtin_bit_cast(u32, e[rb + 2]), 0x07060302u);
          u32 wd = __builtin_amdgcn_perm(__builtin_bit_cast(u32, e[rb + 7]), __builtin_bit_cast(u32, e[rb + 6]), 0x07060302u);
          asm("v_permlane32_swap_b32 %0, %1" : "+v"(wa), "+v"(wb));
          asm("v_permlane32_swap_b32 %0, %1" : "+v"(wc), "+v"(wd));
          pf[t * 2 + sl].w[0] = wa; pf[t * 2 + sl].w[1] = wc;
          pf[t * 2 + sl].w[2] = wb; pf[t * 2 + sl].w[3] = wd;
        }
      }

      // O += P V : vf (B-operand) from V^T LDS; o0 = d 0..31, o1 = d 32..63
      #pragma unroll
      for (int s = 0; s < 4; s++) {
        const int co = ((2 * s + hh) ^ fs8) * 8;
        bf16x8 vf0 = *(const bf16x8*)(sVc + l31 * 64 + co);
        bf16x8 vf1 = *(const bf16x8*)(sVc + (32 + l31) * 64 + co);
        o0 = __builtin_amdgcn_mfma_f32_32x32x16_bf16(pf[s].v, vf0, o0, 0, 0, 0);
        o1 = __builtin_amdgcn_mfma_f32_32x32x16_bf16(pf[s].v, vf1, o1, 0, 0, 0);
      }
    }
  }
  waitv0();  // drain tail junk loads before LDS dealloc at endpgm
#undef STAGEKV

  // epilogue: lane's halves both hold complementary key-sums -> one swap completes it.
  rsum += __shfl_xor(rsum, 32);
  float inv = 1.0f / rsum;   // valid at lane == its query (both halves)
  #pragma unroll
  for (int rg = 0; rg < 16; rg++) {
    const int qr = (rg & 3) + 8 * (rg >> 2) + 4 * hh;  // local q-row of this reg
    float iv = __shfl(inv, qr);
    const size_t rowoff = base + (size_t)(q0w + qr) * 1024;
    ctxb[rowoff + l31] = f2bf(o0[rg] * iv);
    ctxb[rowoff + 32 + l31] = f2bf(o1[rg] * iv);
  }
}

// ---------------- fused residual + split-K reduce (bf16 partials) + LayerNorm ----------------
// out = LN(a + b + c) * g + be ;  a is fp32 (ABF=0) or bf16 (ABF=1); b,c bf16 partials
template <int ABF>
__global__ __launch_bounds__(256) void ln_kernel(const void* __restrict__ a,
                                                 const u16* __restrict__ b,
                                                 const u16* __restrict__ c,
                                                 const float* __restrict__ g,
                                                 const float* __restrict__ be,
                                                 float* __restrict__ of32,
                                                 u16* __restrict__ obf) {
  const int row = blockIdx.x;
  const int tid = threadIdx.x;
  const size_t base = (size_t)row * 1024;
  const int cc = tid * 4;
  float a0, a1, a2, a3;
  if (ABF) {
    uint2 ua = *(const uint2*)((const u16*)a + base + cc);
    a0 = bf2f(ua.x & 0xffff); a1 = bf2f(ua.x >> 16);
    a2 = bf2f(ua.y & 0xffff); a3 = bf2f(ua.y >> 16);
  } else {
    float4 xa = *(const float4*)((const float*)a + base + cc);
    a0 = xa.x; a1 = xa.y; a2 = xa.z; a3 = xa.w;
  }
  uint2 ub = *(const uint2*)(b + base + cc);
  uint2 uc = *(const uint2*)(c + base + cc);
  float v0 = a0 + bf2f(ub.x & 0xffff) + bf2f(uc.x & 0xffff);
  float v1 = a1 + bf2f(ub.x >> 16)    + bf2f(uc.x >> 16);
  float v2 = a2 + bf2f(ub.y & 0xffff) + bf2f(uc.y & 0xffff);
  float v3 = a3 + bf2f(ub.y >> 16)    + bf2f(uc.y >> 16);
  float s1 = v0 + v1 + v2 + v3;
  float s2 = v0 * v0 + v1 * v1 + v2 * v2 + v3 * v3;
  for (int off = 1; off < 64; off <<= 1) {
    s1 += __shfl_xor(s1, off);
    s2 += __shfl_xor(s2, off);
  }
  __shared__ float red[8];
  int wv = tid >> 6;
  if ((tid & 63) == 0) { red[wv] = s1; red[4 + wv] = s2; }
  __syncthreads();
  s1 = red[0] + red[1] + red[2] + red[3];
  s2 = red[4] + red[5] + red[6] + red[7];
  float mu = s1 * (1.0f / 1024.0f);
  float var = s2 * (1.0f / 1024.0f) - mu * mu;
  float rs = rsqrtf(var + 1e-5f);
  float4 gv = *(const float4*)(g + cc);
  float4 bev = *(const float4*)(be + cc);
  float y0 = (v0 - mu) * rs * gv.x + bev.x;
  float y1 = (v1 - mu) * rs * gv.y + bev.y;
  float y2 = (v2 - mu) * rs * gv.z + bev.z;
  float y3 = (v3 - mu) * rs * gv.w + bev.w;
  if (of32) {
    float4 o = make_float4(y0, y1, y2, y3);
    *(float4*)(of32 + base + cc) = o;
  }
  if (obf) {
    uint2 o;
    o.x = (u32)f2bf(y0) | ((u32)f2bf(y1) << 16);
    o.y = (u32)f2bf(y2) | ((u32)f2bf(y3) << 16);
    *(uint2*)(obf + base + cc) = o;
  }
}

// ---------------- launch ----------------
extern "C" void kernel_launch(void* const* d_in, const int* in_sizes, int n_in,
                              void* d_out, int out_size, void* d_ws, size_t ws_size,
                              hipStream_t stream) {
  const int Mtok = 8192, D = 1024, F = 4096, T = 2048;
  const float* x   = (const float*)d_in[0];
  const float* WQ  = (const float*)d_in[1];
  const float* bQ  = (const float*)d_in[2];
  const float* WK  = (const float*)d_in[3];
  const float* bK  = (const float*)d_in[4];
  const float* WV  = (const float*)d_in[5];
  const float* bV  = (const float*)d_in[6];
  const float* WO  = (const float*)d_in[7];
  const float* bO  = (const float*)d_in[8];
  const float* W1  = (const float*)d_in[9];
  const float* b1  = (const float*)d_in[10];
  const float* W2  = (const float*)d_in[11];
  const float* b2  = (const float*)d_in[12];
  const float* g1  = (const float*)d_in[13];
  const float* be1 = (const float*)d_in[14];
  const float* g2  = (const float*)d_in[15];
  const float* be2 = (const float*)d_in[16];

  char* ws = (char*)d_ws;
  const size_t MB = 1024 * 1024;
  u16*  xb     = (u16*)(ws + 0);          // 16 MB (dead after QKV)
  u16*  wqkvb  = (u16*)(ws + 16 * MB);    // 6 MB  (dead after QKV)
  u16*  wob    = (u16*)(ws + 22 * MB);    // 2 MB  (dead after WO)
  u16*  w1b    = (u16*)(ws + 24 * MB);    // 8 MB  (dead after FF1)
  u16*  w2b    = (u16*)(ws + 32 * MB);    // 8 MB  (dead after FF2)
  u16*  qb     = (u16*)(ws + 40 * MB);    // 16 MB (dead after attn)
  u16*  kb     = (u16*)(ws + 56 * MB);    // 16 MB (dead after attn)
  u16*  vtb    = (u16*)(ws + 72 * MB);    // 16 MB, written transposed by QKV (dead after attn)
  u16*  ctxb   = (u16*)(ws + 88 * MB);    // 16 MB (dead after WO)
  u16*  wp0    = (u16*)(ws + 104 * MB);   // 16 MB bf16 partial (dead after ln1)
  u16*  wp1    = (u16*)(ws + 120 * MB);   // 16 MB bf16 partial (dead after ln1)
  u16*  h1b    = (u16*)(ws + 136 * MB);   // 16 MB bf16 LN1 output (live until ln2)
  u16*  ff1b   = (u16*)(ws + 40 * MB);    // 64 MB over qb..ctxb (dead after FF2)
  u16*  fp0    = (u16*)(ws + 0);          // 16 MB bf16 partial over xb
  u16*  fp1    = (u16*)(ws + 16 * MB);    // 16 MB bf16 partial over wqkvb/wob
  float* out   = (float*)d_out;

  dim3 blk(256);
  dim3 blk512(512);
  cvt_all<<<(20 << 20) / 1024, blk, 0, stream>>>(x, WQ, WK, WV, WO, W1, W2,
                                                 xb, wqkvb, wob, w1b, w2b);

  // fused QKV (N=3072): seg0=Q scaled log2(e)/8, seg1=K, seg2=V stored transposed
  gemm256<0, 1, 0><<<dim3(384), blk512, 0, stream>>>(xb, wqkvb, bQ, qb, Mtok, 3072, D,
                                                     bK, kb, bV, vtb, 12);
  attn_mfma<<<dim3(1024), blk, 0, stream>>>(qb, kb, vtb, ctxb, T);

  // WO projection, split-K=2 -> bf16 partials wp0/wp1; ln1 reduces
  gemm256<0, 0, 1><<<dim3(256), blk512, 0, stream>>>(ctxb, wob, bO, wp0, Mtok, D, D,
                                                     nullptr, wp1, nullptr, nullptr, 4);
  ln_kernel<0><<<Mtok, blk, 0, stream>>>(x, wp0, wp1, g1, be1, nullptr, h1b);

  gemm256<1, 0, 0><<<dim3(512), blk512, 0, stream>>>(h1b, w1b, b1, ff1b, Mtok, F, D,
                                                     nullptr, nullptr, nullptr, nullptr, 16);
  // FF2, split-K=2 -> bf16 partials fp0/fp1; ln2 reduces (bf16 residual h1b)
  gemm256<0, 0, 1><<<dim3(256), blk512, 0, stream>>>(ff1b, w2b, b2, fp0, Mtok, D, F,
                                                     nullptr, fp1, nullptr, nullptr, 4);
  ln_kernel<1><<<Mtok, blk, 0, stream>>>(h1b, fp0, fp1, g2, be2, out, (u16*)nullptr);
}

// Round 5
// 488.978 us; speedup vs baseline: 1.0492x; 1.0305x over previous
//
#include <hip/hip_runtime.h>

typedef unsigned short u16;
typedef unsigned int u32;
typedef __bf16 bf16x8 __attribute__((ext_vector_type(8)));
typedef float f32x4 __attribute__((ext_vector_type(4)));
typedef float f32x16 __attribute__((ext_vector_type(16)));

__device__ __forceinline__ u16 f2bf(float f) {
  u32 u = __builtin_bit_cast(u32, f);
  u = (u + 0x7fffu + ((u >> 16) & 1u)) >> 16;
  return (u16)u;
}
__device__ __forceinline__ float bf2f(u16 h) {
  return __builtin_bit_cast(float, ((u32)h) << 16);
}

// async global->LDS, 16B per lane; LDS dest = wave-uniform base + lane*16 [m97/m104]
__device__ __forceinline__ void gll16(const u16* g, u16* l) {
  __builtin_amdgcn_global_load_lds((const __attribute__((address_space(1))) void*)g,
                                   (__attribute__((address_space(3))) void*)l, 16, 0, 0);
}

// raw barrier: NO implicit vmcnt drain (the whole point of the counted pipeline)
__device__ __forceinline__ void barrier() {
  asm volatile("" ::: "memory");
  __builtin_amdgcn_s_barrier();
  asm volatile("" ::: "memory");
}
__device__ __forceinline__ void waitv8() { asm volatile("s_waitcnt vmcnt(8)" ::: "memory"); }
__device__ __forceinline__ void waitv0() { asm volatile("s_waitcnt vmcnt(0)" ::: "memory"); }

// ---------------- all fp32 -> bf16 conversions in one launch ----------------
__global__ __launch_bounds__(256) void cvt_all(const float* __restrict__ x,
                                               const float* __restrict__ WQ,
                                               const float* __restrict__ WK,
                                               const float* __restrict__ WV,
                                               const float* __restrict__ WO,
                                               const float* __restrict__ W1,
                                               const float* __restrict__ W2,
                                               u16* __restrict__ xb,
                                               u16* __restrict__ wqkvb,
                                               u16* __restrict__ wob,
                                               u16* __restrict__ w1b,
                                               u16* __restrict__ w2b) {
  const int S = 1 << 20;
  int i = (blockIdx.x * 256 + threadIdx.x) * 4;
  const float* src;
  u16* dst;
  if (i < 8 * S) { src = x + i; dst = xb + i; }
  else {
    int j = i - 8 * S;
    if (j < 3 * S)      { src = (j < S) ? WQ + j : (j < 2 * S) ? WK + (j - S) : WV + (j - 2 * S);
                          dst = wqkvb + j; }
    else if (j < 4 * S) { src = WO + (j - 3 * S); dst = wob + (j - 3 * S); }
    else if (j < 8 * S) { src = W1 + (j - 4 * S); dst = w1b + (j - 4 * S); }
    else                { src = W2 + (j - 8 * S); dst = w2b + (j - 8 * S); }
  }
  float4 v = *(const float4*)src;
  uint2 o;
  o.x = (u32)f2bf(v.x) | ((u32)f2bf(v.y) << 16);
  o.y = (u32)f2bf(v.z) | ((u32)f2bf(v.w) << 16);
  *(uint2*)dst = o;
}

// ---------------- 256x256 deep-pipelined bf16 MFMA GEMM: C = A @ W^T + bias ----------------
// 512 threads (8 waves, 2M x 4N), BK=32, ring-4 LDS slots (128 KiB total).
// Staging: tile τ's A issued at phase 2τ-6, B at 2τ-5 (prefetch distance 3 tiles);
// steady-state wait = vmcnt(8) once per K-tile (never 0): 8 loads (tiles t+2,t+3)
// stay in flight across barriers [T3+T4]. setprio(1) around each 16-MFMA cluster [T5].
// LDS chunk swizzle applied on BOTH source and ds_read side (rule #21) -> conflict-free.
// QKV=1: N=3072 fused; seg0 = Q scaled 0.125*log2(e), seg1=K, seg2=V transposed.
// SPLIT=1: K halved, kz=0 -> C0 (+bias), kz=1 -> C1 (bf16 partials). N=1024 fixed.
template <int RELU, int QKV, int SPLIT>
__global__ __launch_bounds__(512, 2) void gemm256(const u16* __restrict__ A,
                                                  const u16* __restrict__ W,
                                                  const float* __restrict__ bias0,
                                                  void* __restrict__ C0,
                                                  int M, int N, int K,
                                                  const float* __restrict__ bias1,
                                                  void* __restrict__ C1,
                                                  const float* __restrict__ bias2,
                                                  void* __restrict__ C2,
                                                  int NBN) {
  __shared__ alignas(16) u16 lds[4 * 16384];  // 4 slots x (A 256x32 + B 256x32) u16 = 128 KiB
  const int tid = threadIdx.x;
  const int id = blockIdx.x;
  const int xcd = id & 7, r = id >> 3;
  int bm, bn, kz = 0, koff = 0, KL = K;
  if (SPLIT) {
    bn = (r & 3) << 8;            // N = 1024 fixed
    const int q = r >> 2;         // 0..7
    bm = ((q & 3) * 8 + xcd) << 8;
    kz = q >> 2;
    KL = K >> 1;
    koff = kz * KL;
  } else {
    bn = (r % NBN) << 8;
    bm = ((r / NBN) * 8 + xcd) << 8;
  }
  const int wave = tid >> 6, lane = tid & 63;
  const int lr = lane & 15, quad = lane >> 4;
  const int wm = (wave >> 2) << 7;  // 0 or 128
  const int wn = (wave & 3) << 6;   // 0,64,128,192

  // staging: each gll16 call-site = 8 waves x 1KB = one 128-row half of A or B.
  // wave w covers rows w*16..w*16+15 of the half; lane -> (row = lane>>2, phys chunk = lane&3).
  const int lrow = lane >> 2;
  const int lch = (lane & 3) ^ ((lane >> 3) & 3);  // logical chunk for linear phys dest
  const u16* Asrc = A + (size_t)(bm + wave * 16 + lrow) * K + koff + lch * 8;
  const u16* Wsrc = W + (size_t)(bn + wave * 16 + lrow) * K + koff + lch * 8;
  const size_t half = (size_t)128 * K;
  u16* dstbase = lds + wave * 512;  // u16 units; +4096 = second 128-row half

  const int NT = KL >> 5;
  const int fro = (quad ^ ((lr >> 1) & 3)) * 8;  // swizzled ds_read chunk offset (u16)
  f32x4 acc[8][4] = {};

  // prologue: stage tiles 0,1,2 in consumption order (A then B per tile) = 12 loads/wave
  #pragma unroll
  for (int t = 0; t < 3; t++) {
    u16* d = dstbase + t * 16384;
    gll16(Asrc + (size_t)t * 32, d);
    gll16(Asrc + (size_t)t * 32 + half, d + 4096);
    gll16(Wsrc + (size_t)t * 32, d + 8192);
    gll16(Wsrc + (size_t)t * 32 + half, d + 12288);
  }
  waitv8();   // oldest 4 done = tile 0 fully staged; tiles 1,2 in flight
  barrier();

  for (int t = 0; t < NT; t++) {
    const u16* sa = lds + (t & 3) * 16384;
    const u16* sb = sa + 8192;
    const int tp = (t + 3 < NT) ? t + 3 : NT - 1;  // tail: clamp source (junk slot never read)
    u16* d = dstbase + ((t + 3) & 3) * 16384;
    const size_t ko = (size_t)tp * 32;

    // ---- phase 0: quadrant (mi 0..3) ----
    bf16x8 af[4], bfr[4];
    #pragma unroll
    for (int mi = 0; mi < 4; mi++)
      af[mi] = *(const bf16x8*)(sa + (wm + mi * 16 + lr) * 32 + fro);
    #pragma unroll
    for (int ni = 0; ni < 4; ni++)
      bfr[ni] = *(const bf16x8*)(sb + (wn + ni * 16 + lr) * 32 + fro);
    gll16(Asrc + ko, d);              // stage A(t+3)
    gll16(Asrc + ko + half, d + 4096);
    barrier();
    asm volatile("s_waitcnt lgkmcnt(0)" ::: "memory");
    __builtin_amdgcn_s_setprio(1);
    #pragma unroll
    for (int mi = 0; mi < 4; mi++)
      #pragma unroll
      for (int ni = 0; ni < 4; ni++)
        acc[mi][ni] = __builtin_amdgcn_mfma_f32_16x16x32_bf16(af[mi], bfr[ni], acc[mi][ni], 0, 0, 0);
    __builtin_amdgcn_s_setprio(0);
    barrier();

    // ---- phase 1: quadrant (mi 4..7), reuse bfr ----
    #pragma unroll
    for (int mi = 0; mi < 4; mi++)
      af[mi] = *(const bf16x8*)(sa + (wm + 64 + mi * 16 + lr) * 32 + fro);
    gll16(Wsrc + ko, d + 8192);       // stage B(t+3)
    gll16(Wsrc + ko + half, d + 12288);
    barrier();
    asm volatile("s_waitcnt lgkmcnt(0)" ::: "memory");
    __builtin_amdgcn_s_setprio(1);
    #pragma unroll
    for (int mi = 0; mi < 4; mi++)
      #pragma unroll
      for (int ni = 0; ni < 4; ni++)
        acc[4 + mi][ni] = __builtin_amdgcn_mfma_f32_16x16x32_bf16(af[mi], bfr[ni], acc[4 + mi][ni], 0, 0, 0);
    __builtin_amdgcn_s_setprio(0);
    waitv8();   // covers tile t+1 (8 loads of t+2,t+3 remain in flight)
    barrier();
  }
  waitv0();  // drain tail junk loads before LDS dealloc at endpgm

  // epilogue: C/D layout col=lane&15, row=quad*4+reg [m89/m91]
  const float* bp = bias0;
  void* outp = C0;
  float scale = 1.0f;
  int cb = bn, Nout = N, seg = 0;
  if (QKV) {
    Nout = 1024;
    seg = bn >> 10;
    cb = bn & 1023;
    if (seg == 0) scale = 0.125f * 1.44269504089f;  // 1/sqrt(dk) * log2(e): attn uses exp2
    else if (seg == 1) { bp = bias1; outp = C1; }
    else { bp = bias2; outp = C2; }
  }
  if (SPLIT && kz) outp = C1;

  if (QKV && seg == 2) {
    // V: store transposed. 4 consecutive tokens per lane -> 8B packed stores.
    #pragma unroll
    for (int ni = 0; ni < 4; ni++) {
      const int col = cb + wn + ni * 16 + lr;
      const int hh = col >> 6, dl = col & 63;
      const float bv = bp[col];
      #pragma unroll
      for (int mi = 0; mi < 8; mi++) {
        const int row0 = bm + wm + mi * 16 + quad * 4;
        const int bb = row0 >> 11, tt = row0 & 2047;
        u16 pk[4];
        #pragma unroll
        for (int rg = 0; rg < 4; rg++) pk[rg] = f2bf(acc[mi][ni][rg] + bv);
        uint2 val;
        val.x = (u32)pk[0] | ((u32)pk[1] << 16);
        val.y = (u32)pk[2] | ((u32)pk[3] << 16);
        *(uint2*)(((u16*)outp) + ((size_t)((bb * 16 + hh) * 64 + dl)) * 2048 + tt) = val;
      }
    }
    return;
  }

  #pragma unroll
  for (int ni = 0; ni < 4; ni++) {
    const int col = cb + wn + ni * 16 + lr;
    const float bv = (SPLIT && kz) ? 0.0f : bp[col];
    #pragma unroll
    for (int mi = 0; mi < 8; mi++) {
      #pragma unroll
      for (int rg = 0; rg < 4; rg++) {
        int row = bm + wm + mi * 16 + quad * 4 + rg;
        float v = (acc[mi][ni][rg] + bv) * scale;
        if (RELU) v = fmaxf(v, 0.0f);
        ((u16*)outp)[(size_t)row * Nout + col] = f2bf(v);
      }
    }
  }
}

// ---------------- MFMA flash attention: 32x32, TLP-oriented grid [R4 post-mortem] ----------------
// One 64-query q-tile per block, 2048 blocks (b,h,p) longest-first (p = 31 - i>>6);
// same-bh blocks share an XCD (i&7 = bh&7) for K/V L2 reuse. 4 waves = 2 q-subtiles
// x 2-way k-split (wave>>1 = parity of k-tiles): every wave computes every iter,
// sweep halves (<=16 iters), partials combined through LDS at the end (no HBM).
// Single-buffered staging {barrier; stage 2 tiles; vmcnt(0); barrier; compute}:
// exposed latency is hidden by ~5 co-resident blocks/CU (TLP, m169), not pipelining.
// S^T = K Q^T via mfma_32x32x16(kf, qf): D col=lane&31=query, row=(reg&3)+8*(reg>>2)+4*(lane>>5)=key
// [m74/m101]. Softmax fully in-register (exp2, Q pre-scaled log2(e)/8); truncated-bf16
// v_perm packs + one v_permlane32_swap per word-pair build the PV A-fragment.
__global__ __launch_bounds__(256) void attn_mfma(const u16* __restrict__ qb,
                                                 const u16* __restrict__ kb,
                                                 const u16* __restrict__ vt,
                                                 u16* __restrict__ ctxb, int T) {
  __shared__ alignas(16) u16 shm[4 * 4096];  // [K even][K odd][V even][V odd], 8 KiB each
  const int tid = threadIdx.x;
  const int i = blockIdx.x;
  const int g = i & 63;                      // bh index; i&7 = XCD -> all p of a bh colocated
  const int p = 31 - (i >> 6);               // longest blocks dispatched first
  const int h = g >> 2, b = g & 3;
  const size_t base = ((size_t)(b * T)) * 1024 + h * 64;
  const size_t vbase = ((size_t)((b * 16 + h) * 64)) * T;
  const int lane = tid & 63, wave = tid >> 6;
  const int l31 = lane & 31, hh = lane >> 5;
  const int sub = wave & 1;                  // q-subtile (32 q)
  const int kh = wave >> 1;                  // k-parity handled by this wave
  const int srow = lane >> 3;
  const int sch = ((lane & 7) ^ srow) * 8;
  const int fs8 = l31 & 7;
  const int q0w = p * 64 + sub * 32;

  // Q fragments (B-operand): lane holds Q[q0w+l31][ds*16 + hh*8 + 0..7]
  bf16x8 qf[4];
  #pragma unroll
  for (int ds = 0; ds < 4; ds++) {
    uint4 uq = *(const uint4*)(qb + base + (size_t)(q0w + l31) * 1024 + ds * 16 + hh * 8);
    qf[ds] = __builtin_bit_cast(bf16x8, uq);
  }
  f32x16 o0 = {}, o1 = {};
  float rsum = 0.0f;

  const int NI = (p >> 1) + 1;               // iters; iter j covers k-tiles 2j, 2j+1
  for (int j = 0; j < NI; j++) {
    const int ke = 2 * j;                    // always <= p
    const int ko = (2 * j + 1 <= p) ? 2 * j + 1 : p;  // clamp (clamped tile never computed)
    barrier();                               // prev iter's reads of shm done
    #pragma unroll
    for (int jj = 0; jj < 2; jj++) {
      const int rb = wave * 16 + jj * 8;
      const int rr = rb + srow;
      gll16(kb + base + (size_t)(ke * 64 + rr) * 1024 + sch, shm + rb * 64);
      gll16(kb + base + (size_t)(ko * 64 + rr) * 1024 + sch, shm + 4096 + rb * 64);
      gll16(vt + vbase + (size_t)rr * T + (size_t)(ke * 64) + sch, shm + 8192 + rb * 64);
      gll16(vt + vbase + (size_t)rr * T + (size_t)(ko * 64) + sch, shm + 12288 + rb * 64);
    }
    waitv0();
    barrier();                               // all waves' tiles staged
    const int kt = 2 * j + kh;
    if (kt <= p) {
      const u16* sKc = shm + kh * 4096;
      const u16* sVc = shm + 8192 + kh * 4096;

      // S^T = K Q^T: s0 = keys kt*64+0..31, s1 = +32..63 (row-split by hh)
      f32x16 s0v = {}, s1v = {};
      #pragma unroll
      for (int ds = 0; ds < 4; ds++) {
        const int co = ((2 * ds + hh) ^ fs8) * 8;
        bf16x8 kf0 = *(const bf16x8*)(sKc + l31 * 64 + co);
        bf16x8 kf1 = *(const bf16x8*)(sKc + (32 + l31) * 64 + co);
        s0v = __builtin_amdgcn_mfma_f32_32x32x16_bf16(kf0, qf[ds], s0v, 0, 0, 0);
        s1v = __builtin_amdgcn_mfma_f32_32x32x16_bf16(kf1, qf[ds], s1v, 0, 0, 0);
      }

      // causal mask on the diagonal tile
      if (kt == p) {
        const int qloc = (sub << 5) + l31;
        #pragma unroll
        for (int rg = 0; rg < 16; rg++) {
          const int key = (rg & 3) + 8 * (rg >> 2) + 4 * hh;
          if (key > qloc) s0v[rg] = -1e30f;
          if (key + 32 > qloc) s1v[rg] = -1e30f;
        }
      }

      // P = exp2(S) in-register; row-sum per lane (its own query)
      float e[32];
      #pragma unroll
      for (int rg = 0; rg < 16; rg++) {
        e[rg] = __builtin_amdgcn_exp2f(s0v[rg]);
        e[16 + rg] = __builtin_amdgcn_exp2f(s1v[rg]);
        rsum += e[rg] + e[16 + rg];
      }

      // pack to PV A-fragments: pf[s] = P[q=l31][keys 16s + hh*8 + 0..7]
      union PW { u32 w[4]; bf16x8 v; } pf[4];
      #pragma unroll
      for (int t = 0; t < 2; t++) {
        #pragma unroll
        for (int sl = 0; sl < 2; sl++) {
          const int rb = t * 16 + sl * 8;
          u32 wa = __builtin_amdgcn_perm(__builtin_bit_cast(u32, e[rb + 1]), __builtin_bit_cast(u32, e[rb + 0]), 0x07060302u);
          u32 wb = __builtin_amdgcn_perm(__builtin_bit_cast(u32, e[rb + 5]), __builtin_bit_cast(u32, e[rb + 4]), 0x07060302u);
          u32 wc = __builtin_amdgcn_perm(__builtin_bit_cast(u32, e[rb + 3]), __builtin_bit_cast(u32, e[rb + 2]), 0x07060302u);
          u32 wd = __builtin_amdgcn_perm(__builtin_bit_cast(u32, e[rb + 7]), __builtin_bit_cast(u32, e[rb + 6]), 0x07060302u);
          asm("v_permlane32_swap_b32 %0, %1" : "+v"(wa), "+v"(wb));
          asm("v_permlane32_swap_b32 %0, %1" : "+v"(wc), "+v"(wd));
          pf[t * 2 + sl].w[0] = wa; pf[t * 2 + sl].w[1] = wc;
          pf[t * 2 + sl].w[2] = wb; pf[t * 2 + sl].w[3] = wd;
        }
      }

      // O += P V : vf (B-operand) from V^T LDS; o0 = d 0..31, o1 = d 32..63
      #pragma unroll
      for (int s = 0; s < 4; s++) {
        const int co = ((2 * s + hh) ^ fs8) * 8;
        bf16x8 vf0 = *(const bf16x8*)(sVc + l31 * 64 + co);
        bf16x8 vf1 = *(const bf16x8*)(sVc + (32 + l31) * 64 + co);
        o0 = __builtin_amdgcn_mfma_f32_32x32x16_bf16(pf[s].v, vf0, o0, 0, 0, 0);
        o1 = __builtin_amdgcn_mfma_f32_32x32x16_bf16(pf[s].v, vf1, o1, 0, 0, 0);
      }
    }
  }

  // combine k-parity partials through LDS (shm no longer needed for staging)
  rsum += __shfl_xor(rsum, 32);   // combine hh halves: full partial sum for query l31
  barrier();                      // all waves done reading shm
  float* red = (float*)shm;       // 2 subtiles x (32 o-regs + 1 rsum) x 64 lanes = 4224 f32
  if (kh == 1) {
    #pragma unroll
    for (int rg = 0; rg < 16; rg++) {
      red[sub * 2112 + rg * 64 + lane] = o0[rg];
      red[sub * 2112 + (16 + rg) * 64 + lane] = o1[rg];
    }
    red[sub * 2112 + 2048 + lane] = rsum;
  }
  barrier();
  if (kh == 0) {
    #pragma unroll
    for (int rg = 0; rg < 16; rg++) {
      o0[rg] += red[sub * 2112 + rg * 64 + lane];
      o1[rg] += red[sub * 2112 + (16 + rg) * 64 + lane];
    }
    rsum += red[sub * 2112 + 2048 + lane];
    float inv = 1.0f / rsum;      // valid at lane == its query (both halves)
    #pragma unroll
    for (int rg = 0; rg < 16; rg++) {
      const int qr = (rg & 3) + 8 * (rg >> 2) + 4 * hh;  // local q-row of this reg
      float iv = __shfl(inv, qr);
      const size_t rowoff = base + (size_t)(q0w + qr) * 1024;
      ctxb[rowoff + l31] = f2bf(o0[rg] * iv);
      ctxb[rowoff + 32 + l31] = f2bf(o1[rg] * iv);
    }
  }
}

// ---------------- fused residual + split-K reduce (bf16 partials) + LayerNorm ----------------
// out = LN(a + b + c) * g + be ;  a is fp32 (ABF=0) or bf16 (ABF=1); b,c bf16 partials
template <int ABF>
__global__ __launch_bounds__(256) void ln_kernel(const void* __restrict__ a,
                                                 const u16* __restrict__ b,
                                                 const u16* __restrict__ c,
                                                 const float* __restrict__ g,
                                                 const float* __restrict__ be,
                                                 float* __restrict__ of32,
                                                 u16* __restrict__ obf) {
  const int row = blockIdx.x;
  const int tid = threadIdx.x;
  const size_t base = (size_t)row * 1024;
  const int cc = tid * 4;
  float a0, a1, a2, a3;
  if (ABF) {
    uint2 ua = *(const uint2*)((const u16*)a + base + cc);
    a0 = bf2f(ua.x & 0xffff); a1 = bf2f(ua.x >> 16);
    a2 = bf2f(ua.y & 0xffff); a3 = bf2f(ua.y >> 16);
  } else {
    float4 xa = *(const float4*)((const float*)a + base + cc);
    a0 = xa.x; a1 = xa.y; a2 = xa.z; a3 = xa.w;
  }
  uint2 ub = *(const uint2*)(b + base + cc);
  uint2 uc = *(const uint2*)(c + base + cc);
  float v0 = a0 + bf2f(ub.x & 0xffff) + bf2f(uc.x & 0xffff);
  float v1 = a1 + bf2f(ub.x >> 16)    + bf2f(uc.x >> 16);
  float v2 = a2 + bf2f(ub.y & 0xffff) + bf2f(uc.y & 0xffff);
  float v3 = a3 + bf2f(ub.y >> 16)    + bf2f(uc.y >> 16);
  float s1 = v0 + v1 + v2 + v3;
  float s2 = v0 * v0 + v1 * v1 + v2 * v2 + v3 * v3;
  for (int off = 1; off < 64; off <<= 1) {
    s1 += __shfl_xor(s1, off);
    s2 += __shfl_xor(s2, off);
  }
  __shared__ float red[8];
  int wv = tid >> 6;
  if ((tid & 63) == 0) { red[wv] = s1; red[4 + wv] = s2; }
  __syncthreads();
  s1 = red[0] + red[1] + red[2] + red[3];
  s2 = red[4] + red[5] + red[6] + red[7];
  float mu = s1 * (1.0f / 1024.0f);
  float var = s2 * (1.0f / 1024.0f) - mu * mu;
  float rs = rsqrtf(var + 1e-5f);
  float4 gv = *(const float4*)(g + cc);
  float4 bev = *(const float4*)(be + cc);
  float y0 = (v0 - mu) * rs * gv.x + bev.x;
  float y1 = (v1 - mu) * rs * gv.y + bev.y;
  float y2 = (v2 - mu) * rs * gv.z + bev.z;
  float y3 = (v3 - mu) * rs * gv.w + bev.w;
  if (of32) {
    float4 o = make_float4(y0, y1, y2, y3);
    *(float4*)(of32 + base + cc) = o;
  }
  if (obf) {
    uint2 o;
    o.x = (u32)f2bf(y0) | ((u32)f2bf(y1) << 16);
    o.y = (u32)f2bf(y2) | ((u32)f2bf(y3) << 16);
    *(uint2*)(obf + base + cc) = o;
  }
}

// ---------------- launch ----------------
extern "C" void kernel_launch(void* const* d_in, const int* in_sizes, int n_in,
                              void* d_out, int out_size, void* d_ws, size_t ws_size,
                              hipStream_t stream) {
  const int Mtok = 8192, D = 1024, F = 4096, T = 2048;
  const float* x   = (const float*)d_in[0];
  const float* WQ  = (const float*)d_in[1];
  const float* bQ  = (const float*)d_in[2];
  const float* WK  = (const float*)d_in[3];
  const float* bK  = (const float*)d_in[4];
  const float* WV  = (const float*)d_in[5];
  const float* bV  = (const float*)d_in[6];
  const float* WO  = (const float*)d_in[7];
  const float* bO  = (const float*)d_in[8];
  const float* W1  = (const float*)d_in[9];
  const float* b1  = (const float*)d_in[10];
  const float* W2  = (const float*)d_in[11];
  const float* b2  = (const float*)d_in[12];
  const float* g1  = (const float*)d_in[13];
  const float* be1 = (const float*)d_in[14];
  const float* g2  = (const float*)d_in[15];
  const float* be2 = (const float*)d_in[16];

  char* ws = (char*)d_ws;
  const size_t MB = 1024 * 1024;
  u16*  xb     = (u16*)(ws + 0);          // 16 MB (dead after QKV)
  u16*  wqkvb  = (u16*)(ws + 16 * MB);    // 6 MB  (dead after QKV)
  u16*  wob    = (u16*)(ws + 22 * MB);    // 2 MB  (dead after WO)
  u16*  w1b    = (u16*)(ws + 24 * MB);    // 8 MB  (dead after FF1)
  u16*  w2b    = (u16*)(ws + 32 * MB);    // 8 MB  (dead after FF2)
  u16*  qb     = (u16*)(ws + 40 * MB);    // 16 MB (dead after attn)
  u16*  kb     = (u16*)(ws + 56 * MB);    // 16 MB (dead after attn)
  u16*  vtb    = (u16*)(ws + 72 * MB);    // 16 MB, written transposed by QKV (dead after attn)
  u16*  ctxb   = (u16*)(ws + 88 * MB);    // 16 MB (dead after WO)
  u16*  wp0    = (u16*)(ws + 104 * MB);   // 16 MB bf16 partial (dead after ln1)
  u16*  wp1    = (u16*)(ws + 120 * MB);   // 16 MB bf16 partial (dead after ln1)
  u16*  h1b    = (u16*)(ws + 136 * MB);   // 16 MB bf16 LN1 output (live until ln2)
  u16*  ff1b   = (u16*)(ws + 40 * MB);    // 64 MB over qb..ctxb (dead after FF2)
  u16*  fp0    = (u16*)(ws + 0);          // 16 MB bf16 partial over xb
  u16*  fp1    = (u16*)(ws + 16 * MB);    // 16 MB bf16 partial over wqkvb/wob
  float* out   = (float*)d_out;

  dim3 blk(256);
  dim3 blk512(512);
  cvt_all<<<(20 << 20) / 1024, blk, 0, stream>>>(x, WQ, WK, WV, WO, W1, W2,
                                                 xb, wqkvb, wob, w1b, w2b);

  // fused QKV (N=3072): seg0=Q scaled log2(e)/8, seg1=K, seg2=V stored transposed
  gemm256<0, 1, 0><<<dim3(384), blk512, 0, stream>>>(xb, wqkvb, bQ, qb, Mtok, 3072, D,
                                                     bK, kb, bV, vtb, 12);
  attn_mfma<<<dim3(2048), blk, 0, stream>>>(qb, kb, vtb, ctxb, T);

  // WO projection, split-K=2 -> bf16 partials wp0/wp1; ln1 reduces
  gemm256<0, 0, 1><<<dim3(256), blk512, 0, stream>>>(ctxb, wob, bO, wp0, Mtok, D, D,
                                                     nullptr, wp1, nullptr, nullptr, 4);
  ln_kernel<0><<<Mtok, blk, 0, stream>>>(x, wp0, wp1, g1, be1, nullptr, h1b);

  gemm256<1, 0, 0><<<dim3(512), blk512, 0, stream>>>(h1b, w1b, b1, ff1b, Mtok, F, D,
                                                     nullptr, nullptr, nullptr, nullptr, 16);
  // FF2, split-K=2 -> bf16 partials fp0/fp1; ln2 reduces (bf16 residual h1b)
  gemm256<0, 0, 1><<<dim3(256), blk512, 0, stream>>>(ff1b, w2b, b2, fp0, Mtok, D, F,
                                                     nullptr, fp1, nullptr, nullptr, 4);
  ln_kernel<1><<<Mtok, blk, 0, stream>>>(h1b, fp0, fp1, g2, be2, out, (u16*)nullptr);
}

// Round 6
// 455.140 us; speedup vs baseline: 1.1272x; 1.0743x over previous
//
#include <hip/hip_runtime.h>

typedef unsigned short u16;
typedef unsigned int u32;
typedef __bf16 bf16x8 __attribute__((ext_vector_type(8)));
typedef float f32x4 __attribute__((ext_vector_type(4)));
typedef float f32x16 __attribute__((ext_vector_type(16)));

__device__ __forceinline__ u16 f2bf(float f) {
  u32 u = __builtin_bit_cast(u32, f);
  u = (u + 0x7fffu + ((u >> 16) & 1u)) >> 16;
  return (u16)u;
}
__device__ __forceinline__ float bf2f(u16 h) {
  return __builtin_bit_cast(float, ((u32)h) << 16);
}

// async global->LDS, 16B per lane; LDS dest = wave-uniform base + lane*16 [m97/m104]
__device__ __forceinline__ void gll16(const u16* g, u16* l) {
  __builtin_amdgcn_global_load_lds((const __attribute__((address_space(1))) void*)g,
                                   (__attribute__((address_space(3))) void*)l, 16, 0, 0);
}

// raw barrier: NO implicit vmcnt drain (the whole point of the counted pipeline)
__device__ __forceinline__ void barrier() {
  asm volatile("" ::: "memory");
  __builtin_amdgcn_s_barrier();
  asm volatile("" ::: "memory");
}
__device__ __forceinline__ void waitv3() { asm volatile("s_waitcnt vmcnt(3)" ::: "memory"); }
__device__ __forceinline__ void waitv0() { asm volatile("s_waitcnt vmcnt(0)" ::: "memory"); }

// ---------------- all fp32 -> bf16 conversions in one launch ----------------
__global__ __launch_bounds__(256) void cvt_all(const float* __restrict__ x,
                                               const float* __restrict__ WQ,
                                               const float* __restrict__ WK,
                                               const float* __restrict__ WV,
                                               const float* __restrict__ WO,
                                               const float* __restrict__ W1,
                                               const float* __restrict__ W2,
                                               u16* __restrict__ xb,
                                               u16* __restrict__ wqkvb,
                                               u16* __restrict__ wob,
                                               u16* __restrict__ w1b,
                                               u16* __restrict__ w2b) {
  const int S = 1 << 20;
  int i = (blockIdx.x * 256 + threadIdx.x) * 4;
  const float* src;
  u16* dst;
  if (i < 8 * S) { src = x + i; dst = xb + i; }
  else {
    int j = i - 8 * S;
    if (j < 3 * S)      { src = (j < S) ? WQ + j : (j < 2 * S) ? WK + (j - S) : WV + (j - 2 * S);
                          dst = wqkvb + j; }
    else if (j < 4 * S) { src = WO + (j - 3 * S); dst = wob + (j - 3 * S); }
    else if (j < 8 * S) { src = W1 + (j - 4 * S); dst = w1b + (j - 4 * S); }
    else                { src = W2 + (j - 8 * S); dst = w2b + (j - 8 * S); }
  }
  float4 v = *(const float4*)src;
  uint2 o;
  o.x = (u32)f2bf(v.x) | ((u32)f2bf(v.y) << 16);
  o.y = (u32)f2bf(v.z) | ((u32)f2bf(v.w) << 16);
  *(uint2*)dst = o;
}

// ---------------- 256x128 occupancy-oriented bf16 MFMA GEMM: C = A @ W^T + bias ----------------
// 512 threads (8 waves, 4M x 2N), 64x64 per wave (acc = 64 f32), BK=32,
// ring-2 LDS slots (48 KiB) -> 2 blocks/CU resident; __launch_bounds__(512,4)
// caps VGPR at 128 so occupancy is 4 waves/SIMD. Cross-block TLP hides the
// staging/barrier stalls [R5 post-mortem; m114/m97 mechanism].
// Counted vmcnt kept [T4]: stage(t+1) at top of iter (3 loads/wave: 2xA, 1xB),
// vmcnt(3) == "tile t landed by this wave" + barrier == landed by ALL waves;
// tile t+1's loads stay in flight across the compute (never drain to 0 in loop).
// LDS chunk swizzle: phys16B-chunk = logical ^ ((row>>1)&3) on BOTH the
// pre-swizzled global source and the ds_read side (rule #21) -> conflict-free
// (verified 0 SQ_LDS_BANK_CONFLICT on this pattern since R1).
// QKV=1: N=3072 fused; seg0 = Q scaled 0.125*log2(e), seg1=K, seg2=V transposed.
// SPLIT=1: K halved, kz=0 -> C0 (+bias), kz=1 -> C1 (bf16 partials). N=1024 fixed.
template <int RELU, int QKV, int SPLIT>
__global__ __launch_bounds__(512, 4) void gemm256(const u16* __restrict__ A,
                                                  const u16* __restrict__ W,
                                                  const float* __restrict__ bias0,
                                                  void* __restrict__ C0,
                                                  int M, int N, int K,
                                                  const float* __restrict__ bias1,
                                                  void* __restrict__ C1,
                                                  const float* __restrict__ bias2,
                                                  void* __restrict__ C2,
                                                  int NBN) {
  __shared__ alignas(16) u16 lds[2 * 12288];  // 2 slots x (A 256x32 + B 128x32) u16 = 48 KiB
  const int tid = threadIdx.x;
  const int id = blockIdx.x;
  const int xcd = id & 7, r = id >> 3;
  int bm, bn, kz = 0, koff = 0, KL = K;
  if (SPLIT) {
    bn = (r & 7) << 7;            // 8 n-tiles of 128 (N = 1024 fixed)
    const int q = r >> 3;         // 0..7
    bm = ((q & 3) * 8 + xcd) << 8;
    kz = q >> 2;
    KL = K >> 1;
    koff = kz * KL;
  } else {
    bn = (r % NBN) << 7;
    bm = ((r / NBN) * 8 + xcd) << 8;
  }
  const int wave = tid >> 6, lane = tid & 63;
  const int lr = lane & 15, quad = lane >> 4;
  const int wm = (wave >> 1) << 6;  // 0,64,128,192
  const int wn = (wave & 1) << 6;   // 0,64

  // staging: one gll16 call = 64 lanes x 16B = 16 rows of 32 u16.
  // wave w: A rows [w*32, w*32+32) (2 calls), B rows [w*16, w*16+16) (1 call).
  // dest lane l -> row l>>2, phys 16B-chunk l&3; source logical chunk = (l&3)^((row>>1)&3).
  const int lrow = lane >> 2;
  const int lch = (lane & 3) ^ ((lane >> 3) & 3);
  const u16* Asrc = A + (size_t)(bm + wave * 32 + lrow) * K + koff + lch * 8;
  const u16* Wsrc = W + (size_t)(bn + wave * 16 + lrow) * K + koff + lch * 8;
  const size_t rK16 = (size_t)16 * K;

  const int NT = KL >> 5;
  const int fro = (quad ^ ((lr >> 1) & 3)) * 8;  // swizzled ds_read chunk offset (u16)
  f32x4 acc[4][4] = {};

#define STAGE(tt) { const int tp_ = ((tt) < NT) ? (tt) : NT - 1;   /* tail: junk slot never read */ \
    const size_t ko_ = (size_t)tp_ * 32;                                                            \
    u16* b_ = lds + ((tt) & 1) * 12288;                                                             \
    gll16(Asrc + ko_, b_ + wave * 1024);                                                            \
    gll16(Asrc + ko_ + rK16, b_ + wave * 1024 + 512);                                               \
    gll16(Wsrc + ko_, b_ + 8192 + wave * 512); }

  STAGE(0);  // prologue: tile 0 in flight (3 loads/wave)

  for (int t = 0; t < NT; t++) {
    barrier();              // all waves done reading slot (t+1)&1 (iter t-1's compute)
    STAGE(t + 1);           // prefetch next tile; stays in flight across compute
    waitv3();               // this wave's tile-t loads landed
    barrier();              // => ALL waves' tile-t loads landed
    const u16* sa = lds + (t & 1) * 12288;
    const u16* sb = sa + 8192;
    bf16x8 af[4], bfr[4];
    #pragma unroll
    for (int mi = 0; mi < 4; mi++)
      af[mi] = *(const bf16x8*)(sa + (wm + mi * 16 + lr) * 32 + fro);
    #pragma unroll
    for (int ni = 0; ni < 4; ni++)
      bfr[ni] = *(const bf16x8*)(sb + (wn + ni * 16 + lr) * 32 + fro);
    asm volatile("s_waitcnt lgkmcnt(0)" ::: "memory");
    __builtin_amdgcn_s_setprio(1);
    #pragma unroll
    for (int mi = 0; mi < 4; mi++)
      #pragma unroll
      for (int ni = 0; ni < 4; ni++)
        acc[mi][ni] = __builtin_amdgcn_mfma_f32_16x16x32_bf16(af[mi], bfr[ni], acc[mi][ni], 0, 0, 0);
    __builtin_amdgcn_s_setprio(0);
  }
  waitv0();  // drain tail junk loads before LDS dealloc at endpgm
#undef STAGE

  // epilogue: C/D layout col=lane&15, row=quad*4+reg [m89/m91]
  const float* bp = bias0;
  void* outp = C0;
  float scale = 1.0f;
  int cb = bn, Nout = N, seg = 0;
  if (QKV) {
    Nout = 1024;
    seg = bn >> 10;
    cb = bn & 1023;
    if (seg == 0) scale = 0.125f * 1.44269504089f;  // 1/sqrt(dk) * log2(e): attn uses exp2
    else if (seg == 1) { bp = bias1; outp = C1; }
    else { bp = bias2; outp = C2; }
  }
  if (SPLIT && kz) outp = C1;

  if (QKV && seg == 2) {
    // V: store transposed. 4 consecutive tokens per lane -> 8B packed stores.
    #pragma unroll
    for (int ni = 0; ni < 4; ni++) {
      const int col = cb + wn + ni * 16 + lr;
      const int hh = col >> 6, dl = col & 63;
      const float bv = bp[col];
      #pragma unroll
      for (int mi = 0; mi < 4; mi++) {
        const int row0 = bm + wm + mi * 16 + quad * 4;
        const int bb = row0 >> 11, tt = row0 & 2047;
        u16 pk[4];
        #pragma unroll
        for (int rg = 0; rg < 4; rg++) pk[rg] = f2bf(acc[mi][ni][rg] + bv);
        uint2 val;
        val.x = (u32)pk[0] | ((u32)pk[1] << 16);
        val.y = (u32)pk[2] | ((u32)pk[3] << 16);
        *(uint2*)(((u16*)outp) + ((size_t)((bb * 16 + hh) * 64 + dl)) * 2048 + tt) = val;
      }
    }
    return;
  }

  #pragma unroll
  for (int ni = 0; ni < 4; ni++) {
    const int col = cb + wn + ni * 16 + lr;
    const float bv = (SPLIT && kz) ? 0.0f : bp[col];
    #pragma unroll
    for (int mi = 0; mi < 4; mi++) {
      #pragma unroll
      for (int rg = 0; rg < 4; rg++) {
        int row = bm + wm + mi * 16 + quad * 4 + rg;
        float v = (acc[mi][ni][rg] + bv) * scale;
        if (RELU) v = fmaxf(v, 0.0f);
        ((u16*)outp)[(size_t)row * Nout + col] = f2bf(v);
      }
    }
  }
}

// ---------------- MFMA flash attention: 32x32, TLP-oriented grid [R4 post-mortem] ----------------
// One 64-query q-tile per block, 2048 blocks (b,h,p) longest-first (p = 31 - i>>6);
// same-bh blocks share an XCD (i&7 = bh&7) for K/V L2 reuse. 4 waves = 2 q-subtiles
// x 2-way k-split (wave>>1 = parity of k-tiles): every wave computes every iter,
// sweep halves (<=16 iters), partials combined through LDS at the end (no HBM).
// Single-buffered staging {barrier; stage 2 tiles; vmcnt(0); barrier; compute}:
// exposed latency is hidden by ~5 co-resident blocks/CU (TLP, m169), not pipelining.
// S^T = K Q^T via mfma_32x32x16(kf, qf): D col=lane&31=query, row=(reg&3)+8*(reg>>2)+4*(lane>>5)=key
// [m74/m101]. Softmax fully in-register (exp2, Q pre-scaled log2(e)/8); truncated-bf16
// v_perm packs + one v_permlane32_swap per word-pair build the PV A-fragment.
__global__ __launch_bounds__(256) void attn_mfma(const u16* __restrict__ qb,
                                                 const u16* __restrict__ kb,
                                                 const u16* __restrict__ vt,
                                                 u16* __restrict__ ctxb, int T) {
  __shared__ alignas(16) u16 shm[4 * 4096];  // [K even][K odd][V even][V odd], 8 KiB each
  const int tid = threadIdx.x;
  const int i = blockIdx.x;
  const int g = i & 63;                      // bh index; i&7 = XCD -> all p of a bh colocated
  const int p = 31 - (i >> 6);               // longest blocks dispatched first
  const int h = g >> 2, b = g & 3;
  const size_t base = ((size_t)(b * T)) * 1024 + h * 64;
  const size_t vbase = ((size_t)((b * 16 + h) * 64)) * T;
  const int lane = tid & 63, wave = tid >> 6;
  const int l31 = lane & 31, hh = lane >> 5;
  const int sub = wave & 1;                  // q-subtile (32 q)
  const int kh = wave >> 1;                  // k-parity handled by this wave
  const int srow = lane >> 3;
  const int sch = ((lane & 7) ^ srow) * 8;
  const int fs8 = l31 & 7;
  const int q0w = p * 64 + sub * 32;

  // Q fragments (B-operand): lane holds Q[q0w+l31][ds*16 + hh*8 + 0..7]
  bf16x8 qf[4];
  #pragma unroll
  for (int ds = 0; ds < 4; ds++) {
    uint4 uq = *(const uint4*)(qb + base + (size_t)(q0w + l31) * 1024 + ds * 16 + hh * 8);
    qf[ds] = __builtin_bit_cast(bf16x8, uq);
  }
  f32x16 o0 = {}, o1 = {};
  float rsum = 0.0f;

  const int NI = (p >> 1) + 1;               // iters; iter j covers k-tiles 2j, 2j+1
  for (int j = 0; j < NI; j++) {
    const int ke = 2 * j;                    // always <= p
    const int ko = (2 * j + 1 <= p) ? 2 * j + 1 : p;  // clamp (clamped tile never computed)
    barrier();                               // prev iter's reads of shm done
    #pragma unroll
    for (int jj = 0; jj < 2; jj++) {
      const int rb = wave * 16 + jj * 8;
      const int rr = rb + srow;
      gll16(kb + base + (size_t)(ke * 64 + rr) * 1024 + sch, shm + rb * 64);
      gll16(kb + base + (size_t)(ko * 64 + rr) * 1024 + sch, shm + 4096 + rb * 64);
      gll16(vt + vbase + (size_t)rr * T + (size_t)(ke * 64) + sch, shm + 8192 + rb * 64);
      gll16(vt + vbase + (size_t)rr * T + (size_t)(ko * 64) + sch, shm + 12288 + rb * 64);
    }
    waitv0();
    barrier();                               // all waves' tiles staged
    const int kt = 2 * j + kh;
    if (kt <= p) {
      const u16* sKc = shm + kh * 4096;
      const u16* sVc = shm + 8192 + kh * 4096;

      // S^T = K Q^T: s0 = keys kt*64+0..31, s1 = +32..63 (row-split by hh)
      f32x16 s0v = {}, s1v = {};
      #pragma unroll
      for (int ds = 0; ds < 4; ds++) {
        const int co = ((2 * ds + hh) ^ fs8) * 8;
        bf16x8 kf0 = *(const bf16x8*)(sKc + l31 * 64 + co);
        bf16x8 kf1 = *(const bf16x8*)(sKc + (32 + l31) * 64 + co);
        s0v = __builtin_amdgcn_mfma_f32_32x32x16_bf16(kf0, qf[ds], s0v, 0, 0, 0);
        s1v = __builtin_amdgcn_mfma_f32_32x32x16_bf16(kf1, qf[ds], s1v, 0, 0, 0);
      }

      // causal mask on the diagonal tile
      if (kt == p) {
        const int qloc = (sub << 5) + l31;
        #pragma unroll
        for (int rg = 0; rg < 16; rg++) {
          const int key = (rg & 3) + 8 * (rg >> 2) + 4 * hh;
          if (key > qloc) s0v[rg] = -1e30f;
          if (key + 32 > qloc) s1v[rg] = -1e30f;
        }
      }

      // P = exp2(S) in-register; row-sum per lane (its own query)
      float e[32];
      #pragma unroll
      for (int rg = 0; rg < 16; rg++) {
        e[rg] = __builtin_amdgcn_exp2f(s0v[rg]);
        e[16 + rg] = __builtin_amdgcn_exp2f(s1v[rg]);
        rsum += e[rg] + e[16 + rg];
      }

      // pack to PV A-fragments: pf[s] = P[q=l31][keys 16s + hh*8 + 0..7]
      union PW { u32 w[4]; bf16x8 v; } pf[4];
      #pragma unroll
      for (int t = 0; t < 2; t++) {
        #pragma unroll
        for (int sl = 0; sl < 2; sl++) {
          const int rb = t * 16 + sl * 8;
          u32 wa = __builtin_amdgcn_perm(__builtin_bit_cast(u32, e[rb + 1]), __builtin_bit_cast(u32, e[rb + 0]), 0x07060302u);
          u32 wb = __builtin_amdgcn_perm(__builtin_bit_cast(u32, e[rb + 5]), __builtin_bit_cast(u32, e[rb + 4]), 0x07060302u);
          u32 wc = __builtin_amdgcn_perm(__builtin_bit_cast(u32, e[rb + 3]), __builtin_bit_cast(u32, e[rb + 2]), 0x07060302u);
          u32 wd = __builtin_amdgcn_perm(__builtin_bit_cast(u32, e[rb + 7]), __builtin_bit_cast(u32, e[rb + 6]), 0x07060302u);
          asm("v_permlane32_swap_b32 %0, %1" : "+v"(wa), "+v"(wb));
          asm("v_permlane32_swap_b32 %0, %1" : "+v"(wc), "+v"(wd));
          pf[t * 2 + sl].w[0] = wa; pf[t * 2 + sl].w[1] = wc;
          pf[t * 2 + sl].w[2] = wb; pf[t * 2 + sl].w[3] = wd;
        }
      }

      // O += P V : vf (B-operand) from V^T LDS; o0 = d 0..31, o1 = d 32..63
      #pragma unroll
      for (int s = 0; s < 4; s++) {
        const int co = ((2 * s + hh) ^ fs8) * 8;
        bf16x8 vf0 = *(const bf16x8*)(sVc + l31 * 64 + co);
        bf16x8 vf1 = *(const bf16x8*)(sVc + (32 + l31) * 64 + co);
        o0 = __builtin_amdgcn_mfma_f32_32x32x16_bf16(pf[s].v, vf0, o0, 0, 0, 0);
        o1 = __builtin_amdgcn_mfma_f32_32x32x16_bf16(pf[s].v, vf1, o1, 0, 0, 0);
      }
    }
  }

  // combine k-parity partials through LDS (shm no longer needed for staging)
  rsum += __shfl_xor(rsum, 32);   // combine hh halves: full partial sum for query l31
  barrier();                      // all waves done reading shm
  float* red = (float*)shm;       // 2 subtiles x (32 o-regs + 1 rsum) x 64 lanes = 4224 f32
  if (kh == 1) {
    #pragma unroll
    for (int rg = 0; rg < 16; rg++) {
      red[sub * 2112 + rg * 64 + lane] = o0[rg];
      red[sub * 2112 + (16 + rg) * 64 + lane] = o1[rg];
    }
    red[sub * 2112 + 2048 + lane] = rsum;
  }
  barrier();
  if (kh == 0) {
    #pragma unroll
    for (int rg = 0; rg < 16; rg++) {
      o0[rg] += red[sub * 2112 + rg * 64 + lane];
      o1[rg] += red[sub * 2112 + (16 + rg) * 64 + lane];
    }
    rsum += red[sub * 2112 + 2048 + lane];
    float inv = 1.0f / rsum;      // valid at lane == its query (both halves)
    #pragma unroll
    for (int rg = 0; rg < 16; rg++) {
      const int qr = (rg & 3) + 8 * (rg >> 2) + 4 * hh;  // local q-row of this reg
      float iv = __shfl(inv, qr);
      const size_t rowoff = base + (size_t)(q0w + qr) * 1024;
      ctxb[rowoff + l31] = f2bf(o0[rg] * iv);
      ctxb[rowoff + 32 + l31] = f2bf(o1[rg] * iv);
    }
  }
}

// ---------------- fused residual + split-K reduce (bf16 partials) + LayerNorm ----------------
// out = LN(a + b + c) * g + be ;  a is fp32 (ABF=0) or bf16 (ABF=1); b,c bf16 partials
template <int ABF>
__global__ __launch_bounds__(256) void ln_kernel(const void* __restrict__ a,
                                                 const u16* __restrict__ b,
                                                 const u16* __restrict__ c,
                                                 const float* __restrict__ g,
                                                 const float* __restrict__ be,
                                                 float* __restrict__ of32,
                                                 u16* __restrict__ obf) {
  const int row = blockIdx.x;
  const int tid = threadIdx.x;
  const size_t base = (size_t)row * 1024;
  const int cc = tid * 4;
  float a0, a1, a2, a3;
  if (ABF) {
    uint2 ua = *(const uint2*)((const u16*)a + base + cc);
    a0 = bf2f(ua.x & 0xffff); a1 = bf2f(ua.x >> 16);
    a2 = bf2f(ua.y & 0xffff); a3 = bf2f(ua.y >> 16);
  } else {
    float4 xa = *(const float4*)((const float*)a + base + cc);
    a0 = xa.x; a1 = xa.y; a2 = xa.z; a3 = xa.w;
  }
  uint2 ub = *(const uint2*)(b + base + cc);
  uint2 uc = *(const uint2*)(c + base + cc);
  float v0 = a0 + bf2f(ub.x & 0xffff) + bf2f(uc.x & 0xffff);
  float v1 = a1 + bf2f(ub.x >> 16)    + bf2f(uc.x >> 16);
  float v2 = a2 + bf2f(ub.y & 0xffff) + bf2f(uc.y & 0xffff);
  float v3 = a3 + bf2f(ub.y >> 16)    + bf2f(uc.y >> 16);
  float s1 = v0 + v1 + v2 + v3;
  float s2 = v0 * v0 + v1 * v1 + v2 * v2 + v3 * v3;
  for (int off = 1; off < 64; off <<= 1) {
    s1 += __shfl_xor(s1, off);
    s2 += __shfl_xor(s2, off);
  }
  __shared__ float red[8];
  int wv = tid >> 6;
  if ((tid & 63) == 0) { red[wv] = s1; red[4 + wv] = s2; }
  __syncthreads();
  s1 = red[0] + red[1] + red[2] + red[3];
  s2 = red[4] + red[5] + red[6] + red[7];
  float mu = s1 * (1.0f / 1024.0f);
  float var = s2 * (1.0f / 1024.0f) - mu * mu;
  float rs = rsqrtf(var + 1e-5f);
  float4 gv = *(const float4*)(g + cc);
  float4 bev = *(const float4*)(be + cc);
  float y0 = (v0 - mu) * rs * gv.x + bev.x;
  float y1 = (v1 - mu) * rs * gv.y + bev.y;
  float y2 = (v2 - mu) * rs * gv.z + bev.z;
  float y3 = (v3 - mu) * rs * gv.w + bev.w;
  if (of32) {
    float4 o = make_float4(y0, y1, y2, y3);
    *(float4*)(of32 + base + cc) = o;
  }
  if (obf) {
    uint2 o;
    o.x = (u32)f2bf(y0) | ((u32)f2bf(y1) << 16);
    o.y = (u32)f2bf(y2) | ((u32)f2bf(y3) << 16);
    *(uint2*)(obf + base + cc) = o;
  }
}

// ---------------- launch ----------------
extern "C" void kernel_launch(void* const* d_in, const int* in_sizes, int n_in,
                              void* d_out, int out_size, void* d_ws, size_t ws_size,
                              hipStream_t stream) {
  const int Mtok = 8192, D = 1024, F = 4096, T = 2048;
  const float* x   = (const float*)d_in[0];
  const float* WQ  = (const float*)d_in[1];
  const float* bQ  = (const float*)d_in[2];
  const float* WK  = (const float*)d_in[3];
  const float* bK  = (const float*)d_in[4];
  const float* WV  = (const float*)d_in[5];
  const float* bV  = (const float*)d_in[6];
  const float* WO  = (const float*)d_in[7];
  const float* bO  = (const float*)d_in[8];
  const float* W1  = (const float*)d_in[9];
  const float* b1  = (const float*)d_in[10];
  const float* W2  = (const float*)d_in[11];
  const float* b2  = (const float*)d_in[12];
  const float* g1  = (const float*)d_in[13];
  const float* be1 = (const float*)d_in[14];
  const float* g2  = (const float*)d_in[15];
  const float* be2 = (const float*)d_in[16];

  char* ws = (char*)d_ws;
  const size_t MB = 1024 * 1024;
  u16*  xb     = (u16*)(ws + 0);          // 16 MB (dead after QKV)
  u16*  wqkvb  = (u16*)(ws + 16 * MB);    // 6 MB  (dead after QKV)
  u16*  wob    = (u16*)(ws + 22 * MB);    // 2 MB  (dead after WO)
  u16*  w1b    = (u16*)(ws + 24 * MB);    // 8 MB  (dead after FF1)
  u16*  w2b    = (u16*)(ws + 32 * MB);    // 8 MB  (dead after FF2)
  u16*  qb     = (u16*)(ws + 40 * MB);    // 16 MB (dead after attn)
  u16*  kb     = (u16*)(ws + 56 * MB);    // 16 MB (dead after attn)
  u16*  vtb    = (u16*)(ws + 72 * MB);    // 16 MB, written transposed by QKV (dead after attn)
  u16*  ctxb   = (u16*)(ws + 88 * MB);    // 16 MB (dead after WO)
  u16*  wp0    = (u16*)(ws + 104 * MB);   // 16 MB bf16 partial (dead after ln1)
  u16*  wp1    = (u16*)(ws + 120 * MB);   // 16 MB bf16 partial (dead after ln1)
  u16*  h1b    = (u16*)(ws + 136 * MB);   // 16 MB bf16 LN1 output (live until ln2)
  u16*  ff1b   = (u16*)(ws + 40 * MB);    // 64 MB over qb..ctxb (dead after FF2)
  u16*  fp0    = (u16*)(ws + 0);          // 16 MB bf16 partial over xb
  u16*  fp1    = (u16*)(ws + 16 * MB);    // 16 MB bf16 partial over wqkvb/wob
  float* out   = (float*)d_out;

  dim3 blk(256);
  dim3 blk512(512);
  cvt_all<<<(20 << 20) / 1024, blk, 0, stream>>>(x, WQ, WK, WV, WO, W1, W2,
                                                 xb, wqkvb, wob, w1b, w2b);

  // fused QKV (N=3072): seg0=Q scaled log2(e)/8, seg1=K, seg2=V stored transposed
  gemm256<0, 1, 0><<<dim3(768), blk512, 0, stream>>>(xb, wqkvb, bQ, qb, Mtok, 3072, D,
                                                     bK, kb, bV, vtb, 24);
  attn_mfma<<<dim3(2048), blk, 0, stream>>>(qb, kb, vtb, ctxb, T);

  // WO projection, split-K=2 -> bf16 partials wp0/wp1; ln1 reduces
  gemm256<0, 0, 1><<<dim3(512), blk512, 0, stream>>>(ctxb, wob, bO, wp0, Mtok, D, D,
                                                     nullptr, wp1, nullptr, nullptr, 8);
  ln_kernel<0><<<Mtok, blk, 0, stream>>>(x, wp0, wp1, g1, be1, nullptr, h1b);

  gemm256<1, 0, 0><<<dim3(1024), blk512, 0, stream>>>(h1b, w1b, b1, ff1b, Mtok, F, D,
                                                      nullptr, nullptr, nullptr, nullptr, 32);
  // FF2, split-K=2 -> bf16 partials fp0/fp1; ln2 reduces (bf16 residual h1b)
  gemm256<0, 0, 1><<<dim3(512), blk512, 0, stream>>>(ff1b, w2b, b2, fp0, Mtok, D, F,
                                                     nullptr, fp1, nullptr, nullptr, 8);
  ln_kernel<1><<<Mtok, blk, 0, stream>>>(h1b, fp0, fp1, g2, be2, out, (u16*)nullptr);
}